// Round 18
// baseline (158.500 us; speedup 1.0000x reference)
//
#include <hip/hip_runtime.h>

#define BB 8
#define SS 2048
#define DD 1024
#define BDD 512
#define NSP 64

typedef __attribute__((ext_vector_type(8))) short bf16x8;
typedef __attribute__((ext_vector_type(4))) float f32x4;
typedef unsigned short u16;
typedef unsigned int u32;

__device__ __forceinline__ u16 f2bf(float f) {
  u32 u = __builtin_bit_cast(u32, f);
  u = u + 0x7fffu + ((u >> 16) & 1u);
  return (u16)(u >> 16);
}

__device__ __forceinline__ void gl_lds16(const void* g, void* l) {
  __builtin_amdgcn_global_load_lds((const __attribute__((address_space(1))) void*)g,
                                   (__attribute__((address_space(3))) void*)l,
                                   16, 0, 0);
}

// ---------- merged prep: tok cvt+panelT | infl cvt+panelT+colsum | gate_W^T ----------
// tokT/inflT: s-chunk panels tokT[b][sc][d][64], inflT[b][sc][k][64] (sc=s/64).
// grid 3328: [0,2048) prep_tok (128s x 64d tiles), [2048,2304) prep_infl, [2304,3328) gatewt
__global__ void k_prep(const float* __restrict__ tok, const float* __restrict__ infl,
                       const float* __restrict__ gw, u16* __restrict__ tokbf,
                       u16* __restrict__ tokT, u16* __restrict__ inflbf,
                       u16* __restrict__ inflT, float* __restrict__ rsum,
                       u16* __restrict__ gwt) {
  __shared__ __align__(16) char smraw[128 * 41 * 4];
  u16(*tile)[80] = (u16(*)[80])smraw;
  float(*ps)[64] = (float(*)[64])(smraw + 64 * 80 * 2);
  float(*gt)[33] = (float(*)[33])smraw;
  int bid = blockIdx.x;
  int t = threadIdx.x;

  if (bid < 2048) {
    u32* t32 = (u32*)smraw;
    int C0 = (bid & 15) * 64;
    int R0 = (bid >> 4) * 128;
    int b = R0 >> 11, s0 = R0 & 2047;
    int lc = (t & 7) * 8;
#pragma unroll
    for (int i = 0; i < 4; ++i) {
      int r = (t >> 3) + i * 32;
      const float* src = tok + (size_t)(R0 + r) * DD + C0 + lc;
      float4 a = *(const float4*)src;
      float4 bq = *(const float4*)(src + 4);
      uint4 v;
      v.x = f2bf(a.x) | ((u32)f2bf(a.y) << 16);
      v.y = f2bf(a.z) | ((u32)f2bf(a.w) << 16);
      v.z = f2bf(bq.x) | ((u32)f2bf(bq.y) << 16);
      v.w = f2bf(bq.z) | ((u32)f2bf(bq.w) << 16);
      *(uint4*)(tokbf + (size_t)(R0 + r) * DD + C0 + lc) = v;
      int cbase = r * 41 + (t & 7) * 4;
      t32[cbase + 0] = v.x;
      t32[cbase + 1] = v.y;
      t32[cbase + 2] = v.z;
      t32[cbase + 3] = v.w;
    }
    __syncthreads();
    int dp = t >> 3;
    int si = (t & 7) * 8;
    size_t tb = (size_t)b * DD * SS;
#pragma unroll
    for (int h = 0; h < 2; ++h) {
      int sseg = si + h * 64;
      u32 w[8];
#pragma unroll
      for (int j = 0; j < 8; ++j) w[j] = t32[(sseg + j) * 41 + dp];
      uint4 vlo, vhi;
      vlo.x = (w[0] & 0xffffu) | (w[1] << 16);
      vlo.y = (w[2] & 0xffffu) | (w[3] << 16);
      vlo.z = (w[4] & 0xffffu) | (w[5] << 16);
      vlo.w = (w[6] & 0xffffu) | (w[7] << 16);
      vhi.x = (w[0] >> 16) | (w[1] & 0xffff0000u);
      vhi.y = (w[2] >> 16) | (w[3] & 0xffff0000u);
      vhi.z = (w[4] >> 16) | (w[5] & 0xffff0000u);
      vhi.w = (w[6] >> 16) | (w[7] & 0xffff0000u);
      size_t pbase = tb + (size_t)((s0 >> 6) + h) * (DD * 64);
      *(uint4*)(tokT + pbase + (size_t)(C0 + 2 * dp) * 64 + si) = vlo;
      *(uint4*)(tokT + pbase + (size_t)(C0 + 2 * dp + 1) * 64 + si) = vhi;
    }
  } else if (bid < 2304) {
    int R0 = (bid - 2048) * 64;
    int b = R0 >> 11, s0 = R0 & 2047;
    int st = s0 >> 6;
    int lr = t >> 3, lc = (t & 7) * 8;
    float col[8];
#pragma unroll
    for (int j = 0; j < 8; ++j) col[j] = 0.f;
#pragma unroll
    for (int i = 0; i < 2; ++i) {
      int r = lr + i * 32;
      const float* src = infl + (size_t)(R0 + r) * NSP + lc;
      float4 a = *(const float4*)src;
      float4 bq = *(const float4*)(src + 4);
      col[0] += a.x; col[1] += a.y; col[2] += a.z; col[3] += a.w;
      col[4] += bq.x; col[5] += bq.y; col[6] += bq.z; col[7] += bq.w;
      uint4 v;
      v.x = f2bf(a.x) | ((u32)f2bf(a.y) << 16);
      v.y = f2bf(a.z) | ((u32)f2bf(a.w) << 16);
      v.z = f2bf(bq.x) | ((u32)f2bf(bq.y) << 16);
      v.w = f2bf(bq.z) | ((u32)f2bf(bq.w) << 16);
      *(uint4*)(inflbf + (size_t)(R0 + r) * NSP + lc) = v;
      *(uint4*)&tile[r][lc] = v;
    }
#pragma unroll
    for (int j = 0; j < 8; ++j) ps[lr][lc + j] = col[j];
    __syncthreads();
    if (t < 64) {
      float s = 0.f;
#pragma unroll
      for (int rr = 0; rr < 32; ++rr) s += ps[rr][t];
      rsum[((size_t)b * 32 + st) * 64 + t] = s;
    }
    int sseg = (t & 7) * 8;
    size_t ibase = (size_t)b * NSP * SS + (size_t)st * (NSP * 64);
#pragma unroll
    for (int i = 0; i < 2; ++i) {
      int dcol = (t >> 3) + i * 32;
      u16 a0 = tile[sseg + 0][dcol], a1 = tile[sseg + 1][dcol];
      u16 a2 = tile[sseg + 2][dcol], a3 = tile[sseg + 3][dcol];
      u16 a4 = tile[sseg + 4][dcol], a5 = tile[sseg + 5][dcol];
      u16 a6 = tile[sseg + 6][dcol], a7 = tile[sseg + 7][dcol];
      uint4 v;
      v.x = a0 | ((u32)a1 << 16);
      v.y = a2 | ((u32)a3 << 16);
      v.z = a4 | ((u32)a5 << 16);
      v.w = a6 | ((u32)a7 << 16);
      *(uint4*)(inflT + ibase + (size_t)dcol * 64 + sseg) = v;
    }
  } else {
    int g = bid - 2304;
    int n0 = (g & 31) * 32, k0 = (g >> 5) * 32;
    int tx = t & 31, ty = t >> 5;
#pragma unroll
    for (int r = 0; r < 4; ++r) {
      int kr = ty + r * 8;
      gt[kr][tx] = gw[(k0 + kr) * DD + n0 + tx];
    }
    __syncthreads();
#pragma unroll
    for (int r = 0; r < 4; ++r) {
      int nc = ty + r * 8;
      gwt[(n0 + nc) * DD + k0 + tx] = f2bf(gt[tx][nc]);
    }
  }
}

// ---------- MFMA gather partials: pg[sq][b*64+k][d] (panel-layout inputs) ----------
__global__ __launch_bounds__(256) void k_gather_mfma(const u16* __restrict__ inflT,
                                                     const u16* __restrict__ tokT,
                                                     float* __restrict__ pg) {
  __shared__ u16 As[64 * 64];
  __shared__ u16 Bs[64 * 64];
  int t = threadIdx.x;
  int l = t & 63, w = t >> 6;
  int wr = w >> 1, wc = w & 1;
  int n0 = blockIdx.x * 64;
  int b = blockIdx.y;
  int sq = blockIdx.z;
  int l15 = l & 15, lh = l >> 4;
  int srow = t >> 3, scol = (t & 7) * 8;

  const u16* ap = inflT + (size_t)b * NSP * SS;
  const u16* bp = tokT + (size_t)b * DD * SS;

  f32x4 acc[2][2];
#pragma unroll
  for (int i = 0; i < 2; ++i)
#pragma unroll
    for (int j = 0; j < 2; ++j) acc[i][j] = (f32x4){0.f, 0.f, 0.f, 0.f};

  for (int kt = 0; kt < 8; ++kt) {
    int pc = sq * 8 + kt;
    const u16* app = ap + (size_t)pc * (NSP * 64);
    const u16* bpp = bp + (size_t)pc * (DD * 64);
#pragma unroll
    for (int i = 0; i < 2; ++i) {
      int row = srow + i * 32;
      gl_lds16(app + row * 64 + scol, &As[row * 64 + scol]);
      gl_lds16(bpp + (n0 + row) * 64 + scol, &Bs[row * 64 + scol]);
    }
    __syncthreads();
#pragma unroll
    for (int ks = 0; ks < 2; ++ks) {
      bf16x8 af[2], bfv[2];
#pragma unroll
      for (int mi = 0; mi < 2; ++mi)
        af[mi] = *(const bf16x8*)&As[(wr * 32 + mi * 16 + l15) * 64 + ks * 32 + lh * 8];
#pragma unroll
      for (int ni = 0; ni < 2; ++ni)
        bfv[ni] = *(const bf16x8*)&Bs[(wc * 32 + ni * 16 + l15) * 64 + ks * 32 + lh * 8];
#pragma unroll
      for (int mi = 0; mi < 2; ++mi)
#pragma unroll
        for (int ni = 0; ni < 2; ++ni)
          acc[mi][ni] = __builtin_amdgcn_mfma_f32_16x16x32_bf16(af[mi], bfv[ni], acc[mi][ni], 0, 0, 0);
    }
    __syncthreads();
  }

#pragma unroll
  for (int mi = 0; mi < 2; ++mi)
#pragma unroll
    for (int ni = 0; ni < 2; ++ni)
#pragma unroll
      for (int r = 0; r < 4; ++r) {
        int krow = wr * 32 + mi * 16 + lh * 4 + r;
        int dcol = n0 + wc * 32 + ni * 16 + l15;
        pg[((size_t)sq * 512 + b * NSP + krow) * DD + dcol] = acc[mi][ni][r];
      }
}

// ---------- enc partials (fused gather-reduce + inline rtot): pe[8][m][n], d-slice 128 ----------
__global__ void k_enc_part(const float* __restrict__ pg, const float* __restrict__ rsum,
                           const float* __restrict__ encW, float* __restrict__ pe) {
  __shared__ float gl[8][128];
  int dq = blockIdx.x, mt = blockIdx.y;
  int m0 = mt * 8, d0 = dq * 128;
  int t = threadIdx.x;
  {
    int r = t >> 5, c = t & 31;
    float s[4] = {0.f, 0.f, 0.f, 0.f};
#pragma unroll
    for (int q = 0; q < 4; ++q) {
      const float* qp = pg + ((size_t)q * 512 + m0 + r) * DD + d0;
      s[0] += qp[c]; s[1] += qp[c + 32]; s[2] += qp[c + 64]; s[3] += qp[c + 96];
    }
    int mrow = m0 + r;
    int bq = mrow >> 6, kq = mrow & 63;
    float tt = 0.f;
#pragma unroll
    for (int st = 0; st < 32; ++st) tt += rsum[((size_t)bq * 32 + st) * 64 + kq];
    float rt = 1.f / fmaxf(tt, 1e-8f);
    gl[r][c] = s[0] * rt;
    gl[r][c + 32] = s[1] * rt;
    gl[r][c + 64] = s[2] * rt;
    gl[r][c + 96] = s[3] * rt;
  }
  __syncthreads();
  int n4 = (t & 127) * 4, mh = (t >> 7) * 4;
  float4 acc[4];
#pragma unroll
  for (int m = 0; m < 4; ++m) acc[m] = (float4){0.f, 0.f, 0.f, 0.f};
  for (int i = 0; i < 128; ++i) {
    float4 wv = *(const float4*)(encW + (d0 + i) * BDD + n4);
#pragma unroll
    for (int m = 0; m < 4; ++m) {
      float g = gl[mh + m][i];
      acc[m].x += g * wv.x; acc[m].y += g * wv.y;
      acc[m].z += g * wv.z; acc[m].w += g * wv.w;
    }
  }
#pragma unroll
  for (int m = 0; m < 4; ++m)
    *(float4*)(pe + ((size_t)dq * 512 + m0 + mh + m) * BDD + n4) = acc[m];
}

// ---------- trans partials (fused enc-reduce + bias + relu): pt[8][b*64+ks][e], d-slice 64 ----------
__global__ void k_trans_part(const float* __restrict__ pe, const float* __restrict__ encB,
                             const float* __restrict__ trW, float* __restrict__ pt) {
  __shared__ float el[8][64];
  int dq = blockIdx.x, ks = blockIdx.y;
  int d0 = dq * 64;
  int t = threadIdx.x;
  {
    int r = t >> 5, c = t & 31;
    int m = r * NSP + ks;
    float s1 = 0.f, s2 = 0.f;
#pragma unroll
    for (int p = 0; p < 8; ++p) {
      const float* qp = pe + ((size_t)p * 512 + m) * BDD + d0;
      s1 += qp[c]; s2 += qp[c + 32];
    }
    el[r][c] = fmaxf(s1 + encB[d0 + c], 0.f);
    el[r][c + 32] = fmaxf(s2 + encB[d0 + c + 32], 0.f);
  }
  __syncthreads();
  int n4 = (t & 127) * 4, mh = (t >> 7) * 4;
  float4 acc[4];
#pragma unroll
  for (int m = 0; m < 4; ++m) acc[m] = (float4){0.f, 0.f, 0.f, 0.f};
  for (int i = 0; i < 64; ++i) {
    float4 wv = *(const float4*)(trW + ((size_t)ks * BDD + d0 + i) * BDD + n4);
#pragma unroll
    for (int m = 0; m < 4; ++m) {
      float g = el[mh + m][i];
      acc[m].x += g * wv.x; acc[m].y += g * wv.y;
      acc[m].z += g * wv.z; acc[m].w += g * wv.w;
    }
  }
#pragma unroll
  for (int m = 0; m < 4; ++m)
    *(float4*)(pt + ((size_t)dq * 512 + (mh + m) * NSP + ks) * BDD + n4) = acc[m];
}

// ---------- dec partials (fused trans-reduce + bias): pd[8][m][n] ----------
__global__ void k_dec_part(const float* __restrict__ pt, const float* __restrict__ trB,
                           const float* __restrict__ decW, float* __restrict__ pd) {
  __shared__ float tl[8][64];
  int dq = blockIdx.x, mt = blockIdx.y;
  int m0 = mt * 8, d0 = dq * 64;
  int t = threadIdx.x;
  {
    int r = t >> 5, c = t & 31;
    int m = m0 + r;
    float s1 = 0.f, s2 = 0.f;
#pragma unroll
    for (int p = 0; p < 8; ++p) {
      const float* qp = pt + ((size_t)p * 512 + m) * BDD + d0;
      s1 += qp[c]; s2 += qp[c + 32];
    }
    tl[r][c] = s1 + trB[(m & 63) * BDD + d0 + c];
    tl[r][c + 32] = s2 + trB[(m & 63) * BDD + d0 + c + 32];
  }
  __syncthreads();
  int n4 = t * 4;
  float4 acc[8];
#pragma unroll
  for (int m = 0; m < 8; ++m) acc[m] = (float4){0.f, 0.f, 0.f, 0.f};
  for (int i = 0; i < 64; ++i) {
    float4 wv = *(const float4*)(decW + (d0 + i) * DD + n4);
#pragma unroll
    for (int m = 0; m < 8; ++m) {
      float g = tl[m][i];
      acc[m].x += g * wv.x; acc[m].y += g * wv.y;
      acc[m].z += g * wv.z; acc[m].w += g * wv.w;
    }
  }
#pragma unroll
  for (int m = 0; m < 8; ++m)
    *(float4*)(pd + ((size_t)dq * 512 + m0 + m) * DD + n4) = acc[m];
}

// ---------- reduce dec partials + bias -> decT[b][n][ks] bf16 ----------
__global__ void red_dec(const float* __restrict__ pd, const float* __restrict__ decB,
                        u16* __restrict__ decT) {
  __shared__ u16 st[64][34];
  int nt = blockIdx.x, b = blockIdx.y;
  int n0 = nt * 32;
  int t = threadIdx.x;
  int nn = t & 31, kg = t >> 5;
  float db = decB[n0 + nn];
#pragma unroll
  for (int ki = 0; ki < 8; ++ki) {
    int ks = kg * 8 + ki;
    float s = db;
#pragma unroll
    for (int p = 0; p < 8; ++p)
      s += pd[((size_t)p * 512 + b * NSP + ks) * DD + n0 + nn];
    st[ks][nn] = f2bf(s);
  }
  __syncthreads();
  int nr = t >> 3, kseg = (t & 7) * 8;
  uint4 v;
  v.x = st[kseg + 0][nr] | ((u32)st[kseg + 1][nr] << 16);
  v.y = st[kseg + 2][nr] | ((u32)st[kseg + 3][nr] << 16);
  v.z = st[kseg + 4][nr] | ((u32)st[kseg + 5][nr] << 16);
  v.w = st[kseg + 6][nr] | ((u32)st[kseg + 7][nr] << 16);
  *(uint4*)(decT + ((size_t)b * DD + n0 + nr) * NSP + kseg) = v;
}

// ---------- fused gate GEMM + scatter + sigmoid*flow (progressive epilogue) ----------

#define GVM(n) asm volatile("s_waitcnt vmcnt(" #n ")" ::: "memory");

#define GSTA(sl, k0, p)                                                        \
  { int e = (p)*512 + t; int row = e >> 3; int cs = ((e & 7) ^ (row & 7)) * 8; \
    gl_lds16(tokbf + (size_t)(m0 + row) * DD + (k0) + cs, &As[sl][e * 8]); }
#define GSTB(sl, k0, p)                                                        \
  { int e = (p)*512 + t; int row = e >> 3; int cs = ((e & 7) ^ (row & 7)) * 8; \
    gl_lds16(gwt + (size_t)(n0 + row) * DD + (k0) + cs, &Bs[sl][e * 8]); }
#define SAI(sl, p)                                                             \
  { int e = (p)*512 + t; int row = e >> 3; int cs = ((e & 7) ^ (row & 7)) * 8; \
    gl_lds16(inflbf + ((size_t)bb * SS + s0m + row) * NSP + cs, &As[sl][e * 8]); }
#define SBD(sl, p)                                                             \
  { int e = (p)*512 + t; int row = e >> 3; int cs = ((e & 7) ^ (row & 7)) * 8; \
    gl_lds16(decT + ((size_t)bb * DD + n0 + row) * NSP + cs, &Bs[sl][e * 8]); }

#define GLOADB(sl)                                                             \
  _Pragma("unroll")                                                            \
  for (int nf = 0; nf < 2; ++nf) {                                             \
    int br = wc * 32 + nf * 16 + l15;                                          \
    bfv[nf][0] = *(const bf16x8*)&Bs[sl][br * 64 + c0];                        \
    bfv[nf][1] = *(const bf16x8*)&Bs[sl][br * 64 + c1];                        \
  }

#define GPH(sl, mq, VMW, STG, LDB)                                             \
  {                                                                            \
    VMW                                                                        \
    __builtin_amdgcn_s_barrier();                                              \
    LDB                                                                        \
    bf16x8 af[4][2];                                                           \
    _Pragma("unroll")                                                          \
    for (int mf = 0; mf < 4; ++mf) {                                           \
      int ar = (mq)*64 + mf * 16 + l15;                                        \
      af[mf][0] = *(const bf16x8*)&As[sl][ar * 64 + c0];                       \
      af[mf][1] = *(const bf16x8*)&As[sl][ar * 64 + c1];                       \
    }                                                                          \
    STG                                                                        \
    __builtin_amdgcn_s_setprio(1);                                             \
    _Pragma("unroll")                                                          \
    for (int mf = 0; mf < 4; ++mf)                                             \
      _Pragma("unroll")                                                        \
      for (int nf = 0; nf < 2; ++nf) {                                         \
        acc[(mq)*4 + mf][nf] = __builtin_amdgcn_mfma_f32_16x16x32_bf16(af[mf][0], bfv[nf][0], acc[(mq)*4 + mf][nf], 0, 0, 0); \
        acc[(mq)*4 + mf][nf] = __builtin_amdgcn_mfma_f32_16x16x32_bf16(af[mf][1], bfv[nf][1], acc[(mq)*4 + mf][nf], 0, 0, 0); \
      }                                                                        \
    __builtin_amdgcn_s_setprio(0);                                             \
    __builtin_amdgcn_s_barrier();                                              \
  }

#define GT_FULL(sl, osl, k1)                                                   \
  {                                                                            \
    bf16x8 bfv[2][2];                                                          \
    GPH(sl, 0, GVM(3), GSTB(osl, k1, 0) GSTB(osl, k1, 1), GLOADB(sl))          \
    GPH(sl, 1, GVM(4), GSTB(osl, k1, 2) GSTB(osl, k1, 3), )                    \
    GPH(sl, 2, GVM(5), GSTA(osl, k1, 0) GSTA(osl, k1, 1), )                    \
    GPH(sl, 3, GVM(6), GSTA(osl, k1, 2) GSTA(osl, k1, 3), )                    \
  }
#define GT_LAST2(sl)                                                           \
  {                                                                            \
    bf16x8 bfv[2][2];                                                          \
    GPH(sl, 0, GVM(3), SAI(0, 0) SAI(0, 1), GLOADB(sl))                        \
    GPH(sl, 1, GVM(4), SAI(0, 2) SAI(0, 3), )                                  \
    GPH(sl, 2, GVM(5), SBD(0, 0) SBD(0, 1), )                                  \
    GPH(sl, 3, GVM(6), SBD(0, 2) SBD(0, 3), )                                  \
  }

__global__ __launch_bounds__(512, 1) void k_gate(const u16* __restrict__ tokbf,
                                                 const u16* __restrict__ gwt,
                                                 const u16* __restrict__ inflbf,
                                                 const u16* __restrict__ decT,
                                                 const float* __restrict__ gateB,
                                                 float* __restrict__ outp) {
  __shared__ u16 As[2][256 * 64];
  __shared__ u16 Bs[2][256 * 64];
  int t = threadIdx.x;
  int l = t & 63, wc = t >> 6;
  int bid = blockIdx.x;
  int wg = (bid & 7) * 32 + (bid >> 3);
  int mt = wg & 63, nt = wg >> 6;
  int m0 = mt * 256, n0 = nt * 256;
  int l15 = l & 15, lh = l >> 4;
  int x7 = l15 & 7;
  int c0 = (lh ^ x7) * 8;
  int c1 = ((4 + lh) ^ x7) * 8;
  int bb = m0 >> 11, s0m = m0 & 2047;

  f32x4 acc[16][2];
#pragma unroll
  for (int i = 0; i < 16; ++i)
#pragma unroll
    for (int j = 0; j < 2; ++j) acc[i][j] = (f32x4){0.f, 0.f, 0.f, 0.f};

  GSTB(0, 0, 0) GSTB(0, 0, 1) GSTB(0, 0, 2) GSTB(0, 0, 3)
  GSTA(0, 0, 0) GSTA(0, 0, 1) GSTA(0, 0, 2) GSTA(0, 0, 3)

#pragma unroll 1
  for (int i = 0; i < 7; ++i) {
    GT_FULL(0, 1, (2 * i + 1) * 64)
    GT_FULL(1, 0, (2 * i + 2) * 64)
  }
  GT_FULL(0, 1, 960)
  GT_LAST2(1)

  GVM(0)
  __builtin_amdgcn_s_barrier();

  {
    float gb[2];
#pragma unroll
    for (int nf = 0; nf < 2; ++nf) gb[nf] = gateB[n0 + wc * 32 + nf * 16 + l15];
    bf16x8 bfv[2][2];
    GLOADB(0)
#pragma unroll
    for (int mq = 0; mq < 4; ++mq) {
      bf16x8 af[4][2];
#pragma unroll
      for (int mf = 0; mf < 4; ++mf) {
        int ar = mq * 64 + mf * 16 + l15;
        af[mf][0] = *(const bf16x8*)&As[0][ar * 64 + c0];
        af[mf][1] = *(const bf16x8*)&As[0][ar * 64 + c1];
      }
      f32x4 accf[4][2];
#pragma unroll
      for (int mf = 0; mf < 4; ++mf)
#pragma unroll
        for (int nf = 0; nf < 2; ++nf) accf[mf][nf] = (f32x4){0.f, 0.f, 0.f, 0.f};
      __builtin_amdgcn_s_setprio(1);
#pragma unroll
      for (int mf = 0; mf < 4; ++mf)
#pragma unroll
        for (int nf = 0; nf < 2; ++nf) {
          accf[mf][nf] = __builtin_amdgcn_mfma_f32_16x16x32_bf16(af[mf][0], bfv[nf][0], accf[mf][nf], 0, 0, 0);
          accf[mf][nf] = __builtin_amdgcn_mfma_f32_16x16x32_bf16(af[mf][1], bfv[nf][1], accf[mf][nf], 0, 0, 0);
        }
      __builtin_amdgcn_s_setprio(0);
#pragma unroll
      for (int mf = 0; mf < 4; ++mf)
#pragma unroll
        for (int nf = 0; nf < 2; ++nf)
#pragma unroll
          for (int r = 0; r < 4; ++r) {
            int mr = m0 + (mq * 4 + mf) * 16 + lh * 4 + r;
            int nc = n0 + wc * 32 + nf * 16 + l15;
            float z = acc[mq * 4 + mf][nf][r] + gb[nf];
            float gate = 1.f / (1.f + __expf(-z));
            outp[(size_t)mr * DD + nc] = accf[mf][nf][r] * gate;
          }
    }
  }
}

extern "C" void kernel_launch(void* const* d_in, const int* in_sizes, int n_in,
                              void* d_out, int out_size, void* d_ws, size_t ws_size,
                              hipStream_t stream) {
  const float* tok = (const float*)d_in[0];
  const float* infl = (const float*)d_in[1];
  const float* encW = (const float*)d_in[2];
  const float* encB = (const float*)d_in[3];
  const float* trW = (const float*)d_in[4];
  const float* trB = (const float*)d_in[5];
  const float* decW = (const float*)d_in[6];
  const float* decB = (const float*)d_in[7];
  const float* gw = (const float*)d_in[8];
  const float* gateB = (const float*)d_in[9];
  float* outp = (float*)d_out;

  char* wsp = (char*)d_ws;
  u16* tokbf = (u16*)(wsp);                    // 33,554,432 B
  u16* gwt = (u16*)(wsp + 33554432);           //  2,097,152 B
  u16* inflbf = (u16*)(wsp + 35651584);        //  2,097,152 B
  u16* decT = (u16*)(wsp + 41945088);          //  1,048,576 B
  u16* tokT = (u16*)(wsp + 42993664);          // 33,554,432 B (dead after gather)
  float* pe = (float*)(wsp + 42993664);        //   overlays tokT[0:8MB]
  float* pt = (float*)(wsp + 42993664 + 8388608);   // overlays tokT[8:16MB]
  u16* inflT = (u16*)(wsp + 76548096);         //  2,097,152 B
  float* rsum = (float*)(wsp + 78645248);      //     65,536 B
  float* scratch = (float*)(wsp + 78710784);   // 16,777,216 B: pg then pd

  k_prep<<<dim3(3328), dim3(256), 0, stream>>>(tok, infl, gw, tokbf, tokT, inflbf,
                                               inflT, rsum, gwt);
  k_gather_mfma<<<dim3(16, 8, 4), dim3(256), 0, stream>>>(inflT, tokT, scratch);
  k_enc_part<<<dim3(8, 64), dim3(256), 0, stream>>>(scratch, rsum, encW, pe);
  k_trans_part<<<dim3(8, 64), dim3(256), 0, stream>>>(pe, encB, trW, pt);
  k_dec_part<<<dim3(8, 64), dim3(256), 0, stream>>>(pt, trB, decW, scratch);
  red_dec<<<dim3(32, 8), dim3(256), 0, stream>>>(scratch, decB, decT);
  k_gate<<<dim3(256), dim3(512), 0, stream>>>(tokbf, gwt, inflbf, decT, gateB, outp);
}

// Round 19
// 150.306 us; speedup vs baseline: 1.0545x; 1.0545x over previous
//
#include <hip/hip_runtime.h>

#define BB 8
#define SS 2048
#define DD 1024
#define BDD 512
#define NSP 64

typedef __attribute__((ext_vector_type(8))) short bf16x8;
typedef __attribute__((ext_vector_type(4))) float f32x4;
typedef unsigned short u16;
typedef unsigned int u32;

__device__ __forceinline__ u16 f2bf(float f) {
  u32 u = __builtin_bit_cast(u32, f);
  u = u + 0x7fffu + ((u >> 16) & 1u);
  return (u16)(u >> 16);
}

__device__ __forceinline__ void gl_lds16(const void* g, void* l) {
  __builtin_amdgcn_global_load_lds((const __attribute__((address_space(1))) void*)g,
                                   (__attribute__((address_space(3))) void*)l,
                                   16, 0, 0);
}

// ---------- merged prep: tok streaming cvt | infl cvt+panelT+colsum | gate_W^T ----------
// grid 9472: [0,8192) tok cvt (no LDS), [8192,8448) infl, [8448,9472) gatewt
__global__ void k_prep(const float* __restrict__ tok, const float* __restrict__ infl,
                       const float* __restrict__ gw, u16* __restrict__ tokbf,
                       u16* __restrict__ inflbf, u16* __restrict__ inflT,
                       float* __restrict__ rsum, u16* __restrict__ gwt) {
  __shared__ __align__(16) char smraw[64 * 80 * 2 + 32 * 64 * 4];
  u16(*tile)[80] = (u16(*)[80])smraw;
  float(*ps)[64] = (float(*)[64])(smraw + 64 * 80 * 2);
  float(*gt)[33] = (float(*)[33])smraw;
  int bid = blockIdx.x;
  int t = threadIdx.x;

  if (bid < 8192) {
    // ---- tok: f32 -> tokbf bf16, pure streaming ----
    size_t i = ((size_t)bid * 256 + t) * 8;
    float4 a = *(const float4*)(tok + i);
    float4 bq = *(const float4*)(tok + i + 4);
    uint4 v;
    v.x = f2bf(a.x) | ((u32)f2bf(a.y) << 16);
    v.y = f2bf(a.z) | ((u32)f2bf(a.w) << 16);
    v.z = f2bf(bq.x) | ((u32)f2bf(bq.y) << 16);
    v.w = f2bf(bq.z) | ((u32)f2bf(bq.w) << 16);
    *(uint4*)(tokbf + i) = v;
  } else if (bid < 8448) {
    // ---- infl: f32 -> inflbf + inflT panels [b][sc][k][64] + col sums ----
    int R0 = (bid - 8192) * 64;
    int b = R0 >> 11, s0 = R0 & 2047;
    int st = s0 >> 6;
    int lr = t >> 3, lc = (t & 7) * 8;
    float col[8];
#pragma unroll
    for (int j = 0; j < 8; ++j) col[j] = 0.f;
#pragma unroll
    for (int i = 0; i < 2; ++i) {
      int r = lr + i * 32;
      const float* src = infl + (size_t)(R0 + r) * NSP + lc;
      float4 a = *(const float4*)src;
      float4 bq = *(const float4*)(src + 4);
      col[0] += a.x; col[1] += a.y; col[2] += a.z; col[3] += a.w;
      col[4] += bq.x; col[5] += bq.y; col[6] += bq.z; col[7] += bq.w;
      uint4 v;
      v.x = f2bf(a.x) | ((u32)f2bf(a.y) << 16);
      v.y = f2bf(a.z) | ((u32)f2bf(a.w) << 16);
      v.z = f2bf(bq.x) | ((u32)f2bf(bq.y) << 16);
      v.w = f2bf(bq.z) | ((u32)f2bf(bq.w) << 16);
      *(uint4*)(inflbf + (size_t)(R0 + r) * NSP + lc) = v;
      *(uint4*)&tile[r][lc] = v;
    }
#pragma unroll
    for (int j = 0; j < 8; ++j) ps[lr][lc + j] = col[j];
    __syncthreads();
    if (t < 64) {
      float s = 0.f;
#pragma unroll
      for (int rr = 0; rr < 32; ++rr) s += ps[rr][t];
      rsum[((size_t)b * 32 + st) * 64 + t] = s;
    }
    int sseg = (t & 7) * 8;
    size_t ibase = (size_t)b * NSP * SS + (size_t)st * (NSP * 64);
#pragma unroll
    for (int i = 0; i < 2; ++i) {
      int dcol = (t >> 3) + i * 32;
      u16 a0 = tile[sseg + 0][dcol], a1 = tile[sseg + 1][dcol];
      u16 a2 = tile[sseg + 2][dcol], a3 = tile[sseg + 3][dcol];
      u16 a4 = tile[sseg + 4][dcol], a5 = tile[sseg + 5][dcol];
      u16 a6 = tile[sseg + 6][dcol], a7 = tile[sseg + 7][dcol];
      uint4 v;
      v.x = a0 | ((u32)a1 << 16);
      v.y = a2 | ((u32)a3 << 16);
      v.z = a4 | ((u32)a5 << 16);
      v.w = a6 | ((u32)a7 << 16);
      *(uint4*)(inflT + ibase + (size_t)dcol * 64 + sseg) = v;
    }
  } else {
    // ---- gate_W [k][n] f32 -> gwt [n][k] bf16 ----
    int g = bid - 8448;
    int n0 = (g & 31) * 32, k0 = (g >> 5) * 32;
    int tx = t & 31, ty = t >> 5;
#pragma unroll
    for (int r = 0; r < 4; ++r) {
      int kr = ty + r * 8;
      gt[kr][tx] = gw[(k0 + kr) * DD + n0 + tx];
    }
    __syncthreads();
#pragma unroll
    for (int r = 0; r < 4; ++r) {
      int nc = ty + r * 8;
      gwt[(n0 + nc) * DD + k0 + tx] = f2bf(gt[tx][nc]);
    }
  }
}

// ---------- MFMA gather partials: pg[sq][b*64+k][d] ----------
// A = inflT panels via gl_lds16 (unchanged). B = tokbf reg-staged with
// in-LDS transpose: thread (s = t>>2, dseg = (t&3)*16) loads 16 bf16 along d
// and writes them to Bs[d*64 + s]; frag-read path identical to r18.
__global__ __launch_bounds__(256) void k_gather_mfma(const u16* __restrict__ inflT,
                                                     const u16* __restrict__ tokbf,
                                                     float* __restrict__ pg) {
  __shared__ u16 As[64 * 64];
  __shared__ u16 Bs[64 * 64];
  int t = threadIdx.x;
  int l = t & 63, w = t >> 6;
  int wr = w >> 1, wc = w & 1;
  int n0 = blockIdx.x * 64;
  int b = blockIdx.y;
  int sq = blockIdx.z;
  int l15 = l & 15, lh = l >> 4;
  int srow = t >> 3, scol = (t & 7) * 8;

  const u16* ap = inflT + (size_t)b * NSP * SS;
  int s = t >> 2;
  int dseg = (t & 3) * 16;

  f32x4 acc[2][2];
#pragma unroll
  for (int i = 0; i < 2; ++i)
#pragma unroll
    for (int j = 0; j < 2; ++j) acc[i][j] = (f32x4){0.f, 0.f, 0.f, 0.f};

  for (int kt = 0; kt < 8; ++kt) {
    int pc = sq * 8 + kt;
    const u16* app = ap + (size_t)pc * (NSP * 64);
#pragma unroll
    for (int i = 0; i < 2; ++i) {
      int row = srow + i * 32;
      gl_lds16(app + row * 64 + scol, &As[row * 64 + scol]);
    }
    {
      const u16* src = tokbf + ((size_t)(b * SS + pc * 64 + s)) * DD + n0 + dseg;
      uint4 q0 = *(const uint4*)src;
      uint4 q1 = *(const uint4*)(src + 8);
      u32 wd0 = q0.x, wd1 = q0.y, wd2 = q0.z, wd3 = q0.w;
      u32 wd4 = q1.x, wd5 = q1.y, wd6 = q1.z, wd7 = q1.w;
      Bs[(dseg + 0) * 64 + s] = (u16)wd0;
      Bs[(dseg + 1) * 64 + s] = (u16)(wd0 >> 16);
      Bs[(dseg + 2) * 64 + s] = (u16)wd1;
      Bs[(dseg + 3) * 64 + s] = (u16)(wd1 >> 16);
      Bs[(dseg + 4) * 64 + s] = (u16)wd2;
      Bs[(dseg + 5) * 64 + s] = (u16)(wd2 >> 16);
      Bs[(dseg + 6) * 64 + s] = (u16)wd3;
      Bs[(dseg + 7) * 64 + s] = (u16)(wd3 >> 16);
      Bs[(dseg + 8) * 64 + s] = (u16)wd4;
      Bs[(dseg + 9) * 64 + s] = (u16)(wd4 >> 16);
      Bs[(dseg + 10) * 64 + s] = (u16)wd5;
      Bs[(dseg + 11) * 64 + s] = (u16)(wd5 >> 16);
      Bs[(dseg + 12) * 64 + s] = (u16)wd6;
      Bs[(dseg + 13) * 64 + s] = (u16)(wd6 >> 16);
      Bs[(dseg + 14) * 64 + s] = (u16)wd7;
      Bs[(dseg + 15) * 64 + s] = (u16)(wd7 >> 16);
    }
    __syncthreads();
#pragma unroll
    for (int ks = 0; ks < 2; ++ks) {
      bf16x8 af[2], bfv[2];
#pragma unroll
      for (int mi = 0; mi < 2; ++mi)
        af[mi] = *(const bf16x8*)&As[(wr * 32 + mi * 16 + l15) * 64 + ks * 32 + lh * 8];
#pragma unroll
      for (int ni = 0; ni < 2; ++ni)
        bfv[ni] = *(const bf16x8*)&Bs[(wc * 32 + ni * 16 + l15) * 64 + ks * 32 + lh * 8];
#pragma unroll
      for (int mi = 0; mi < 2; ++mi)
#pragma unroll
        for (int ni = 0; ni < 2; ++ni)
          acc[mi][ni] = __builtin_amdgcn_mfma_f32_16x16x32_bf16(af[mi], bfv[ni], acc[mi][ni], 0, 0, 0);
    }
    __syncthreads();
  }

#pragma unroll
  for (int mi = 0; mi < 2; ++mi)
#pragma unroll
    for (int ni = 0; ni < 2; ++ni)
#pragma unroll
      for (int r = 0; r < 4; ++r) {
        int krow = wr * 32 + mi * 16 + lh * 4 + r;
        int dcol = n0 + wc * 32 + ni * 16 + l15;
        pg[((size_t)sq * 512 + b * NSP + krow) * DD + dcol] = acc[mi][ni][r];
      }
}

// ---------- enc partials (fused gather-reduce + inline rtot): pe[8][m][n], d-slice 128 ----------
__global__ void k_enc_part(const float* __restrict__ pg, const float* __restrict__ rsum,
                           const float* __restrict__ encW, float* __restrict__ pe) {
  __shared__ float gl[8][128];
  int dq = blockIdx.x, mt = blockIdx.y;
  int m0 = mt * 8, d0 = dq * 128;
  int t = threadIdx.x;
  {
    int r = t >> 5, c = t & 31;
    float s[4] = {0.f, 0.f, 0.f, 0.f};
#pragma unroll
    for (int q = 0; q < 4; ++q) {
      const float* qp = pg + ((size_t)q * 512 + m0 + r) * DD + d0;
      s[0] += qp[c]; s[1] += qp[c + 32]; s[2] += qp[c + 64]; s[3] += qp[c + 96];
    }
    int mrow = m0 + r;
    int bq = mrow >> 6, kq = mrow & 63;
    float tt = 0.f;
#pragma unroll
    for (int st = 0; st < 32; ++st) tt += rsum[((size_t)bq * 32 + st) * 64 + kq];
    float rt = 1.f / fmaxf(tt, 1e-8f);
    gl[r][c] = s[0] * rt;
    gl[r][c + 32] = s[1] * rt;
    gl[r][c + 64] = s[2] * rt;
    gl[r][c + 96] = s[3] * rt;
  }
  __syncthreads();
  int n4 = (t & 127) * 4, mh = (t >> 7) * 4;
  float4 acc[4];
#pragma unroll
  for (int m = 0; m < 4; ++m) acc[m] = (float4){0.f, 0.f, 0.f, 0.f};
  for (int i = 0; i < 128; ++i) {
    float4 wv = *(const float4*)(encW + (d0 + i) * BDD + n4);
#pragma unroll
    for (int m = 0; m < 4; ++m) {
      float g = gl[mh + m][i];
      acc[m].x += g * wv.x; acc[m].y += g * wv.y;
      acc[m].z += g * wv.z; acc[m].w += g * wv.w;
    }
  }
#pragma unroll
  for (int m = 0; m < 4; ++m)
    *(float4*)(pe + ((size_t)dq * 512 + m0 + mh + m) * BDD + n4) = acc[m];
}

// ---------- trans partials (fused enc-reduce + bias + relu): pt[8][b*64+ks][e], d-slice 64 ----------
__global__ void k_trans_part(const float* __restrict__ pe, const float* __restrict__ encB,
                             const float* __restrict__ trW, float* __restrict__ pt) {
  __shared__ float el[8][64];
  int dq = blockIdx.x, ks = blockIdx.y;
  int d0 = dq * 64;
  int t = threadIdx.x;
  {
    int r = t >> 5, c = t & 31;
    int m = r * NSP + ks;
    float s1 = 0.f, s2 = 0.f;
#pragma unroll
    for (int p = 0; p < 8; ++p) {
      const float* qp = pe + ((size_t)p * 512 + m) * BDD + d0;
      s1 += qp[c]; s2 += qp[c + 32];
    }
    el[r][c] = fmaxf(s1 + encB[d0 + c], 0.f);
    el[r][c + 32] = fmaxf(s2 + encB[d0 + c + 32], 0.f);
  }
  __syncthreads();
  int n4 = (t & 127) * 4, mh = (t >> 7) * 4;
  float4 acc[4];
#pragma unroll
  for (int m = 0; m < 4; ++m) acc[m] = (float4){0.f, 0.f, 0.f, 0.f};
  for (int i = 0; i < 64; ++i) {
    float4 wv = *(const float4*)(trW + ((size_t)ks * BDD + d0 + i) * BDD + n4);
#pragma unroll
    for (int m = 0; m < 4; ++m) {
      float g = el[mh + m][i];
      acc[m].x += g * wv.x; acc[m].y += g * wv.y;
      acc[m].z += g * wv.z; acc[m].w += g * wv.w;
    }
  }
#pragma unroll
  for (int m = 0; m < 4; ++m)
    *(float4*)(pt + ((size_t)dq * 512 + (mh + m) * NSP + ks) * BDD + n4) = acc[m];
}

// ---------- dec partials (fused trans-reduce + bias): pd[8][m][n] ----------
__global__ void k_dec_part(const float* __restrict__ pt, const float* __restrict__ trB,
                           const float* __restrict__ decW, float* __restrict__ pd) {
  __shared__ float tl[8][64];
  int dq = blockIdx.x, mt = blockIdx.y;
  int m0 = mt * 8, d0 = dq * 64;
  int t = threadIdx.x;
  {
    int r = t >> 5, c = t & 31;
    int m = m0 + r;
    float s1 = 0.f, s2 = 0.f;
#pragma unroll
    for (int p = 0; p < 8; ++p) {
      const float* qp = pt + ((size_t)p * 512 + m) * BDD + d0;
      s1 += qp[c]; s2 += qp[c + 32];
    }
    tl[r][c] = s1 + trB[(m & 63) * BDD + d0 + c];
    tl[r][c + 32] = s2 + trB[(m & 63) * BDD + d0 + c + 32];
  }
  __syncthreads();
  int n4 = t * 4;
  float4 acc[8];
#pragma unroll
  for (int m = 0; m < 8; ++m) acc[m] = (float4){0.f, 0.f, 0.f, 0.f};
  for (int i = 0; i < 64; ++i) {
    float4 wv = *(const float4*)(decW + (d0 + i) * DD + n4);
#pragma unroll
    for (int m = 0; m < 8; ++m) {
      float g = tl[m][i];
      acc[m].x += g * wv.x; acc[m].y += g * wv.y;
      acc[m].z += g * wv.z; acc[m].w += g * wv.w;
    }
  }
#pragma unroll
  for (int m = 0; m < 8; ++m)
    *(float4*)(pd + ((size_t)dq * 512 + m0 + m) * DD + n4) = acc[m];
}

// ---------- reduce dec partials + bias -> decT[b][n][ks] bf16 ----------
__global__ void red_dec(const float* __restrict__ pd, const float* __restrict__ decB,
                        u16* __restrict__ decT) {
  __shared__ u16 st[64][34];
  int nt = blockIdx.x, b = blockIdx.y;
  int n0 = nt * 32;
  int t = threadIdx.x;
  int nn = t & 31, kg = t >> 5;
  float db = decB[n0 + nn];
#pragma unroll
  for (int ki = 0; ki < 8; ++ki) {
    int ks = kg * 8 + ki;
    float s = db;
#pragma unroll
    for (int p = 0; p < 8; ++p)
      s += pd[((size_t)p * 512 + b * NSP + ks) * DD + n0 + nn];
    st[ks][nn] = f2bf(s);
  }
  __syncthreads();
  int nr = t >> 3, kseg = (t & 7) * 8;
  uint4 v;
  v.x = st[kseg + 0][nr] | ((u32)st[kseg + 1][nr] << 16);
  v.y = st[kseg + 2][nr] | ((u32)st[kseg + 3][nr] << 16);
  v.z = st[kseg + 4][nr] | ((u32)st[kseg + 5][nr] << 16);
  v.w = st[kseg + 6][nr] | ((u32)st[kseg + 7][nr] << 16);
  *(uint4*)(decT + ((size_t)b * DD + n0 + nr) * NSP + kseg) = v;
}

// ---------- fused gate GEMM + scatter + sigmoid*flow (progressive epilogue) ----------

#define GVM(n) asm volatile("s_waitcnt vmcnt(" #n ")" ::: "memory");

#define GSTA(sl, k0, p)                                                        \
  { int e = (p)*512 + t; int row = e >> 3; int cs = ((e & 7) ^ (row & 7)) * 8; \
    gl_lds16(tokbf + (size_t)(m0 + row) * DD + (k0) + cs, &As[sl][e * 8]); }
#define GSTB(sl, k0, p)                                                        \
  { int e = (p)*512 + t; int row = e >> 3; int cs = ((e & 7) ^ (row & 7)) * 8; \
    gl_lds16(gwt + (size_t)(n0 + row) * DD + (k0) + cs, &Bs[sl][e * 8]); }
#define SAI(sl, p)                                                             \
  { int e = (p)*512 + t; int row = e >> 3; int cs = ((e & 7) ^ (row & 7)) * 8; \
    gl_lds16(inflbf + ((size_t)bb * SS + s0m + row) * NSP + cs, &As[sl][e * 8]); }
#define SBD(sl, p)                                                             \
  { int e = (p)*512 + t; int row = e >> 3; int cs = ((e & 7) ^ (row & 7)) * 8; \
    gl_lds16(decT + ((size_t)bb * DD + n0 + row) * NSP + cs, &Bs[sl][e * 8]); }

#define GLOADB(sl)                                                             \
  _Pragma("unroll")                                                            \
  for (int nf = 0; nf < 2; ++nf) {                                             \
    int br = wc * 32 + nf * 16 + l15;                                          \
    bfv[nf][0] = *(const bf16x8*)&Bs[sl][br * 64 + c0];                        \
    bfv[nf][1] = *(const bf16x8*)&Bs[sl][br * 64 + c1];                        \
  }

#define GPH(sl, mq, VMW, STG, LDB)                                             \
  {                                                                            \
    VMW                                                                        \
    __builtin_amdgcn_s_barrier();                                              \
    LDB                                                                        \
    bf16x8 af[4][2];                                                           \
    _Pragma("unroll")                                                          \
    for (int mf = 0; mf < 4; ++mf) {                                           \
      int ar = (mq)*64 + mf * 16 + l15;                                        \
      af[mf][0] = *(const bf16x8*)&As[sl][ar * 64 + c0];                       \
      af[mf][1] = *(const bf16x8*)&As[sl][ar * 64 + c1];                       \
    }                                                                          \
    STG                                                                        \
    __builtin_amdgcn_s_setprio(1);                                             \
    _Pragma("unroll")                                                          \
    for (int mf = 0; mf < 4; ++mf)                                             \
      _Pragma("unroll")                                                        \
      for (int nf = 0; nf < 2; ++nf) {                                         \
        acc[(mq)*4 + mf][nf] = __builtin_amdgcn_mfma_f32_16x16x32_bf16(af[mf][0], bfv[nf][0], acc[(mq)*4 + mf][nf], 0, 0, 0); \
        acc[(mq)*4 + mf][nf] = __builtin_amdgcn_mfma_f32_16x16x32_bf16(af[mf][1], bfv[nf][1], acc[(mq)*4 + mf][nf], 0, 0, 0); \
      }                                                                        \
    __builtin_amdgcn_s_setprio(0);                                             \
    __builtin_amdgcn_s_barrier();                                              \
  }

#define GT_FULL(sl, osl, k1)                                                   \
  {                                                                            \
    bf16x8 bfv[2][2];                                                          \
    GPH(sl, 0, GVM(3), GSTB(osl, k1, 0) GSTB(osl, k1, 1), GLOADB(sl))          \
    GPH(sl, 1, GVM(4), GSTB(osl, k1, 2) GSTB(osl, k1, 3), )                    \
    GPH(sl, 2, GVM(5), GSTA(osl, k1, 0) GSTA(osl, k1, 1), )                    \
    GPH(sl, 3, GVM(6), GSTA(osl, k1, 2) GSTA(osl, k1, 3), )                    \
  }
#define GT_LAST2(sl)                                                           \
  {                                                                            \
    bf16x8 bfv[2][2];                                                          \
    GPH(sl, 0, GVM(3), SAI(0, 0) SAI(0, 1), GLOADB(sl))                        \
    GPH(sl, 1, GVM(4), SAI(0, 2) SAI(0, 3), )                                  \
    GPH(sl, 2, GVM(5), SBD(0, 0) SBD(0, 1), )                                  \
    GPH(sl, 3, GVM(6), SBD(0, 2) SBD(0, 3), )                                  \
  }

__global__ __launch_bounds__(512, 1) void k_gate(const u16* __restrict__ tokbf,
                                                 const u16* __restrict__ gwt,
                                                 const u16* __restrict__ inflbf,
                                                 const u16* __restrict__ decT,
                                                 const float* __restrict__ gateB,
                                                 float* __restrict__ outp) {
  __shared__ u16 As[2][256 * 64];
  __shared__ u16 Bs[2][256 * 64];
  int t = threadIdx.x;
  int l = t & 63, wc = t >> 6;
  int bid = blockIdx.x;
  int wg = (bid & 7) * 32 + (bid >> 3);
  int mt = wg & 63, nt = wg >> 6;
  int m0 = mt * 256, n0 = nt * 256;
  int l15 = l & 15, lh = l >> 4;
  int x7 = l15 & 7;
  int c0 = (lh ^ x7) * 8;
  int c1 = ((4 + lh) ^ x7) * 8;
  int bb = m0 >> 11, s0m = m0 & 2047;

  f32x4 acc[16][2];
#pragma unroll
  for (int i = 0; i < 16; ++i)
#pragma unroll
    for (int j = 0; j < 2; ++j) acc[i][j] = (f32x4){0.f, 0.f, 0.f, 0.f};

  GSTB(0, 0, 0) GSTB(0, 0, 1) GSTB(0, 0, 2) GSTB(0, 0, 3)
  GSTA(0, 0, 0) GSTA(0, 0, 1) GSTA(0, 0, 2) GSTA(0, 0, 3)

#pragma unroll 1
  for (int i = 0; i < 7; ++i) {
    GT_FULL(0, 1, (2 * i + 1) * 64)
    GT_FULL(1, 0, (2 * i + 2) * 64)
  }
  GT_FULL(0, 1, 960)
  GT_LAST2(1)

  GVM(0)
  __builtin_amdgcn_s_barrier();

  {
    float gb[2];
#pragma unroll
    for (int nf = 0; nf < 2; ++nf) gb[nf] = gateB[n0 + wc * 32 + nf * 16 + l15];
    bf16x8 bfv[2][2];
    GLOADB(0)
#pragma unroll
    for (int mq = 0; mq < 4; ++mq) {
      bf16x8 af[4][2];
#pragma unroll
      for (int mf = 0; mf < 4; ++mf) {
        int ar = mq * 64 + mf * 16 + l15;
        af[mf][0] = *(const bf16x8*)&As[0][ar * 64 + c0];
        af[mf][1] = *(const bf16x8*)&As[0][ar * 64 + c1];
      }
      f32x4 accf[4][2];
#pragma unroll
      for (int mf = 0; mf < 4; ++mf)
#pragma unroll
        for (int nf = 0; nf < 2; ++nf) accf[mf][nf] = (f32x4){0.f, 0.f, 0.f, 0.f};
      __builtin_amdgcn_s_setprio(1);
#pragma unroll
      for (int mf = 0; mf < 4; ++mf)
#pragma unroll
        for (int nf = 0; nf < 2; ++nf) {
          accf[mf][nf] = __builtin_amdgcn_mfma_f32_16x16x32_bf16(af[mf][0], bfv[nf][0], accf[mf][nf], 0, 0, 0);
          accf[mf][nf] = __builtin_amdgcn_mfma_f32_16x16x32_bf16(af[mf][1], bfv[nf][1], accf[mf][nf], 0, 0, 0);
        }
      __builtin_amdgcn_s_setprio(0);
#pragma unroll
      for (int mf = 0; mf < 4; ++mf)
#pragma unroll
        for (int nf = 0; nf < 2; ++nf)
#pragma unroll
          for (int r = 0; r < 4; ++r) {
            int mr = m0 + (mq * 4 + mf) * 16 + lh * 4 + r;
            int nc = n0 + wc * 32 + nf * 16 + l15;
            float z = acc[mq * 4 + mf][nf][r] + gb[nf];
            float gate = 1.f / (1.f + __expf(-z));
            outp[(size_t)mr * DD + nc] = accf[mf][nf][r] * gate;
          }
    }
  }
}

extern "C" void kernel_launch(void* const* d_in, const int* in_sizes, int n_in,
                              void* d_out, int out_size, void* d_ws, size_t ws_size,
                              hipStream_t stream) {
  const float* tok = (const float*)d_in[0];
  const float* infl = (const float*)d_in[1];
  const float* encW = (const float*)d_in[2];
  const float* encB = (const float*)d_in[3];
  const float* trW = (const float*)d_in[4];
  const float* trB = (const float*)d_in[5];
  const float* decW = (const float*)d_in[6];
  const float* decB = (const float*)d_in[7];
  const float* gw = (const float*)d_in[8];
  const float* gateB = (const float*)d_in[9];
  float* outp = (float*)d_out;

  char* wsp = (char*)d_ws;
  u16* tokbf = (u16*)(wsp);                    // 33,554,432 B
  u16* gwt = (u16*)(wsp + 33554432);           //  2,097,152 B
  u16* inflbf = (u16*)(wsp + 35651584);        //  2,097,152 B
  u16* decT = (u16*)(wsp + 41945088);          //  1,048,576 B
  float* pe = (float*)(wsp + 42993664);        //  8,388,608 B
  float* pt = (float*)(wsp + 42993664 + 8388608);   // 8,388,608 B
  u16* inflT = (u16*)(wsp + 76548096);         //  2,097,152 B
  float* rsum = (float*)(wsp + 78645248);      //     65,536 B
  float* scratch = (float*)(wsp + 78710784);   // 16,777,216 B: pg then pd

  k_prep<<<dim3(9472), dim3(256), 0, stream>>>(tok, infl, gw, tokbf, inflbf,
                                               inflT, rsum, gwt);
  k_gather_mfma<<<dim3(16, 8, 4), dim3(256), 0, stream>>>(inflT, tokbf, scratch);
  k_enc_part<<<dim3(8, 64), dim3(256), 0, stream>>>(scratch, rsum, encW, pe);
  k_trans_part<<<dim3(8, 64), dim3(256), 0, stream>>>(pe, encB, trW, pt);
  k_dec_part<<<dim3(8, 64), dim3(256), 0, stream>>>(pt, trB, decW, scratch);
  red_dec<<<dim3(32, 8), dim3(256), 0, stream>>>(scratch, decB, decT);
  k_gate<<<dim3(256), dim3(512), 0, stream>>>(tokbf, gwt, inflbf, decT, gateB, outp);
}

// Round 20
// 148.382 us; speedup vs baseline: 1.0682x; 1.0130x over previous
//
#include <hip/hip_runtime.h>

#define BB 8
#define SS 2048
#define DD 1024
#define BDD 512
#define NSP 64

typedef __attribute__((ext_vector_type(8))) short bf16x8;
typedef __attribute__((ext_vector_type(4))) float f32x4;
typedef unsigned short u16;
typedef unsigned int u32;

__device__ __forceinline__ u16 f2bf(float f) {
  u32 u = __builtin_bit_cast(u32, f);
  u = u + 0x7fffu + ((u >> 16) & 1u);
  return (u16)(u >> 16);
}

__device__ __forceinline__ void gl_lds16(const void* g, void* l) {
  __builtin_amdgcn_global_load_lds((const __attribute__((address_space(1))) void*)g,
                                   (__attribute__((address_space(3))) void*)l,
                                   16, 0, 0);
}

// ---------- merged prep: tok streaming cvt | infl cvt+panelT+colsum | gate_W^T ----------
// grid 9472: [0,8192) tok cvt (no LDS), [8192,8448) infl, [8448,9472) gatewt
__global__ void k_prep(const float* __restrict__ tok, const float* __restrict__ infl,
                       const float* __restrict__ gw, u16* __restrict__ tokbf,
                       u16* __restrict__ inflbf, u16* __restrict__ inflT,
                       float* __restrict__ rsum, u16* __restrict__ gwt) {
  __shared__ __align__(16) char smraw[64 * 80 * 2 + 32 * 64 * 4];
  u16(*tile)[80] = (u16(*)[80])smraw;
  float(*ps)[64] = (float(*)[64])(smraw + 64 * 80 * 2);
  float(*gt)[33] = (float(*)[33])smraw;
  int bid = blockIdx.x;
  int t = threadIdx.x;

  if (bid < 8192) {
    size_t i = ((size_t)bid * 256 + t) * 8;
    float4 a = *(const float4*)(tok + i);
    float4 bq = *(const float4*)(tok + i + 4);
    uint4 v;
    v.x = f2bf(a.x) | ((u32)f2bf(a.y) << 16);
    v.y = f2bf(a.z) | ((u32)f2bf(a.w) << 16);
    v.z = f2bf(bq.x) | ((u32)f2bf(bq.y) << 16);
    v.w = f2bf(bq.z) | ((u32)f2bf(bq.w) << 16);
    *(uint4*)(tokbf + i) = v;
  } else if (bid < 8448) {
    int R0 = (bid - 8192) * 64;
    int b = R0 >> 11, s0 = R0 & 2047;
    int st = s0 >> 6;
    int lr = t >> 3, lc = (t & 7) * 8;
    float col[8];
#pragma unroll
    for (int j = 0; j < 8; ++j) col[j] = 0.f;
#pragma unroll
    for (int i = 0; i < 2; ++i) {
      int r = lr + i * 32;
      const float* src = infl + (size_t)(R0 + r) * NSP + lc;
      float4 a = *(const float4*)src;
      float4 bq = *(const float4*)(src + 4);
      col[0] += a.x; col[1] += a.y; col[2] += a.z; col[3] += a.w;
      col[4] += bq.x; col[5] += bq.y; col[6] += bq.z; col[7] += bq.w;
      uint4 v;
      v.x = f2bf(a.x) | ((u32)f2bf(a.y) << 16);
      v.y = f2bf(a.z) | ((u32)f2bf(a.w) << 16);
      v.z = f2bf(bq.x) | ((u32)f2bf(bq.y) << 16);
      v.w = f2bf(bq.z) | ((u32)f2bf(bq.w) << 16);
      *(uint4*)(inflbf + (size_t)(R0 + r) * NSP + lc) = v;
      *(uint4*)&tile[r][lc] = v;
    }
#pragma unroll
    for (int j = 0; j < 8; ++j) ps[lr][lc + j] = col[j];
    __syncthreads();
    if (t < 64) {
      float s = 0.f;
#pragma unroll
      for (int rr = 0; rr < 32; ++rr) s += ps[rr][t];
      rsum[((size_t)b * 32 + st) * 64 + t] = s;
    }
    int sseg = (t & 7) * 8;
    size_t ibase = (size_t)b * NSP * SS + (size_t)st * (NSP * 64);
#pragma unroll
    for (int i = 0; i < 2; ++i) {
      int dcol = (t >> 3) + i * 32;
      u16 a0 = tile[sseg + 0][dcol], a1 = tile[sseg + 1][dcol];
      u16 a2 = tile[sseg + 2][dcol], a3 = tile[sseg + 3][dcol];
      u16 a4 = tile[sseg + 4][dcol], a5 = tile[sseg + 5][dcol];
      u16 a6 = tile[sseg + 6][dcol], a7 = tile[sseg + 7][dcol];
      uint4 v;
      v.x = a0 | ((u32)a1 << 16);
      v.y = a2 | ((u32)a3 << 16);
      v.z = a4 | ((u32)a5 << 16);
      v.w = a6 | ((u32)a7 << 16);
      *(uint4*)(inflT + ibase + (size_t)dcol * 64 + sseg) = v;
    }
  } else {
    int g = bid - 8448;
    int n0 = (g & 31) * 32, k0 = (g >> 5) * 32;
    int tx = t & 31, ty = t >> 5;
#pragma unroll
    for (int r = 0; r < 4; ++r) {
      int kr = ty + r * 8;
      gt[kr][tx] = gw[(k0 + kr) * DD + n0 + tx];
    }
    __syncthreads();
#pragma unroll
    for (int r = 0; r < 4; ++r) {
      int nc = ty + r * 8;
      gwt[(n0 + nc) * DD + k0 + tx] = f2bf(gt[tx][nc]);
    }
  }
}

// ---------- MFMA gather partials: pg[sq][b*64+k][d] ----------
// A: inflT panels, XOR-swizzled both sides (k_gate's verified involution:
//    src chunk (e&7)^(row&7), read chunk g^(ar&7)).
// B: tokbf reg-staged transpose, element (d,s) -> d*64 + ((s>>3)^((d>>3)&7))*8
//    + (s&7); read chunk g^((br>>3)&7). Write 2-way, read 2-way (free).
__global__ __launch_bounds__(256) void k_gather_mfma(const u16* __restrict__ inflT,
                                                     const u16* __restrict__ tokbf,
                                                     float* __restrict__ pg) {
  __shared__ u16 As[64 * 64];
  __shared__ u16 Bs[64 * 64];
  int t = threadIdx.x;
  int l = t & 63, w = t >> 6;
  int wr = w >> 1, wc = w & 1;
  int n0 = blockIdx.x * 64;
  int b = blockIdx.y;
  int sq = blockIdx.z;
  int l15 = l & 15, lh = l >> 4;

  const u16* ap = inflT + (size_t)b * NSP * SS;
  int s = t >> 2;
  int dseg = (t & 3) * 16;

  f32x4 acc[2][2];
#pragma unroll
  for (int i = 0; i < 2; ++i)
#pragma unroll
    for (int j = 0; j < 2; ++j) acc[i][j] = (f32x4){0.f, 0.f, 0.f, 0.f};

  for (int kt = 0; kt < 8; ++kt) {
    int pc = sq * 8 + kt;
    const u16* app = ap + (size_t)pc * (NSP * 64);
#pragma unroll
    for (int i = 0; i < 2; ++i) {
      int e = i * 256 + t;
      int row = e >> 3;
      int cs = ((e & 7) ^ (row & 7)) * 8;
      gl_lds16(app + row * 64 + cs, &As[e * 8]);
    }
    {
      const u16* src = tokbf + ((size_t)(b * SS + pc * 64 + s)) * DD + n0 + dseg;
      uint4 q0 = *(const uint4*)src;
      uint4 q1 = *(const uint4*)(src + 8);
      u32 wd[8] = {q0.x, q0.y, q0.z, q0.w, q1.x, q1.y, q1.z, q1.w};
      int shi = (s >> 3), slo = (s & 7);
#pragma unroll
      for (int p = 0; p < 8; ++p) {
        int d0 = dseg + p * 2, d1 = dseg + p * 2 + 1;
        Bs[d0 * 64 + ((shi ^ ((d0 >> 3) & 7)) * 8) + slo] = (u16)wd[p];
        Bs[d1 * 64 + ((shi ^ ((d1 >> 3) & 7)) * 8) + slo] = (u16)(wd[p] >> 16);
      }
    }
    __syncthreads();
#pragma unroll
    for (int ks = 0; ks < 2; ++ks) {
      int g = ks * 4 + lh;
      bf16x8 af[2], bfv[2];
#pragma unroll
      for (int mi = 0; mi < 2; ++mi) {
        int ar = wr * 32 + mi * 16 + l15;
        af[mi] = *(const bf16x8*)&As[ar * 64 + ((g ^ (ar & 7)) * 8)];
      }
#pragma unroll
      for (int ni = 0; ni < 2; ++ni) {
        int br = wc * 32 + ni * 16 + l15;
        bfv[ni] = *(const bf16x8*)&Bs[br * 64 + ((g ^ ((br >> 3) & 7)) * 8)];
      }
#pragma unroll
      for (int mi = 0; mi < 2; ++mi)
#pragma unroll
        for (int ni = 0; ni < 2; ++ni)
          acc[mi][ni] = __builtin_amdgcn_mfma_f32_16x16x32_bf16(af[mi], bfv[ni], acc[mi][ni], 0, 0, 0);
    }
    __syncthreads();
  }

#pragma unroll
  for (int mi = 0; mi < 2; ++mi)
#pragma unroll
    for (int ni = 0; ni < 2; ++ni)
#pragma unroll
      for (int r = 0; r < 4; ++r) {
        int krow = wr * 32 + mi * 16 + lh * 4 + r;
        int dcol = n0 + wc * 32 + ni * 16 + l15;
        pg[((size_t)sq * 512 + b * NSP + krow) * DD + dcol] = acc[mi][ni][r];
      }
}

// ---------- enc partials (fused gather-reduce + inline rtot): pe[8][m][n], d-slice 128 ----------
__global__ void k_enc_part(const float* __restrict__ pg, const float* __restrict__ rsum,
                           const float* __restrict__ encW, float* __restrict__ pe) {
  __shared__ float gl[8][128];
  int dq = blockIdx.x, mt = blockIdx.y;
  int m0 = mt * 8, d0 = dq * 128;
  int t = threadIdx.x;
  {
    int r = t >> 5, c = t & 31;
    float s[4] = {0.f, 0.f, 0.f, 0.f};
#pragma unroll
    for (int q = 0; q < 4; ++q) {
      const float* qp = pg + ((size_t)q * 512 + m0 + r) * DD + d0;
      s[0] += qp[c]; s[1] += qp[c + 32]; s[2] += qp[c + 64]; s[3] += qp[c + 96];
    }
    int mrow = m0 + r;
    int bq = mrow >> 6, kq = mrow & 63;
    float tt = 0.f;
#pragma unroll
    for (int st = 0; st < 32; ++st) tt += rsum[((size_t)bq * 32 + st) * 64 + kq];
    float rt = 1.f / fmaxf(tt, 1e-8f);
    gl[r][c] = s[0] * rt;
    gl[r][c + 32] = s[1] * rt;
    gl[r][c + 64] = s[2] * rt;
    gl[r][c + 96] = s[3] * rt;
  }
  __syncthreads();
  int n4 = (t & 127) * 4, mh = (t >> 7) * 4;
  float4 acc[4];
#pragma unroll
  for (int m = 0; m < 4; ++m) acc[m] = (float4){0.f, 0.f, 0.f, 0.f};
  for (int i = 0; i < 128; ++i) {
    float4 wv = *(const float4*)(encW + (d0 + i) * BDD + n4);
#pragma unroll
    for (int m = 0; m < 4; ++m) {
      float g = gl[mh + m][i];
      acc[m].x += g * wv.x; acc[m].y += g * wv.y;
      acc[m].z += g * wv.z; acc[m].w += g * wv.w;
    }
  }
#pragma unroll
  for (int m = 0; m < 4; ++m)
    *(float4*)(pe + ((size_t)dq * 512 + m0 + mh + m) * BDD + n4) = acc[m];
}

// ---------- trans partials (fused enc-reduce + bias + relu): pt[8][b*64+ks][e], d-slice 64 ----------
__global__ void k_trans_part(const float* __restrict__ pe, const float* __restrict__ encB,
                             const float* __restrict__ trW, float* __restrict__ pt) {
  __shared__ float el[8][64];
  int dq = blockIdx.x, ks = blockIdx.y;
  int d0 = dq * 64;
  int t = threadIdx.x;
  {
    int r = t >> 5, c = t & 31;
    int m = r * NSP + ks;
    float s1 = 0.f, s2 = 0.f;
#pragma unroll
    for (int p = 0; p < 8; ++p) {
      const float* qp = pe + ((size_t)p * 512 + m) * BDD + d0;
      s1 += qp[c]; s2 += qp[c + 32];
    }
    el[r][c] = fmaxf(s1 + encB[d0 + c], 0.f);
    el[r][c + 32] = fmaxf(s2 + encB[d0 + c + 32], 0.f);
  }
  __syncthreads();
  int n4 = (t & 127) * 4, mh = (t >> 7) * 4;
  float4 acc[4];
#pragma unroll
  for (int m = 0; m < 4; ++m) acc[m] = (float4){0.f, 0.f, 0.f, 0.f};
  for (int i = 0; i < 64; ++i) {
    float4 wv = *(const float4*)(trW + ((size_t)ks * BDD + d0 + i) * BDD + n4);
#pragma unroll
    for (int m = 0; m < 4; ++m) {
      float g = el[mh + m][i];
      acc[m].x += g * wv.x; acc[m].y += g * wv.y;
      acc[m].z += g * wv.z; acc[m].w += g * wv.w;
    }
  }
#pragma unroll
  for (int m = 0; m < 4; ++m)
    *(float4*)(pt + ((size_t)dq * 512 + (mh + m) * NSP + ks) * BDD + n4) = acc[m];
}

// ---------- dec partials (fused trans-reduce + bias): pd[8][m][n] ----------
__global__ void k_dec_part(const float* __restrict__ pt, const float* __restrict__ trB,
                           const float* __restrict__ decW, float* __restrict__ pd) {
  __shared__ float tl[8][64];
  int dq = blockIdx.x, mt = blockIdx.y;
  int m0 = mt * 8, d0 = dq * 64;
  int t = threadIdx.x;
  {
    int r = t >> 5, c = t & 31;
    int m = m0 + r;
    float s1 = 0.f, s2 = 0.f;
#pragma unroll
    for (int p = 0; p < 8; ++p) {
      const float* qp = pt + ((size_t)p * 512 + m) * BDD + d0;
      s1 += qp[c]; s2 += qp[c + 32];
    }
    tl[r][c] = s1 + trB[(m & 63) * BDD + d0 + c];
    tl[r][c + 32] = s2 + trB[(m & 63) * BDD + d0 + c + 32];
  }
  __syncthreads();
  int n4 = t * 4;
  float4 acc[8];
#pragma unroll
  for (int m = 0; m < 8; ++m) acc[m] = (float4){0.f, 0.f, 0.f, 0.f};
  for (int i = 0; i < 64; ++i) {
    float4 wv = *(const float4*)(decW + (d0 + i) * DD + n4);
#pragma unroll
    for (int m = 0; m < 8; ++m) {
      float g = tl[m][i];
      acc[m].x += g * wv.x; acc[m].y += g * wv.y;
      acc[m].z += g * wv.z; acc[m].w += g * wv.w;
    }
  }
#pragma unroll
  for (int m = 0; m < 8; ++m)
    *(float4*)(pd + ((size_t)dq * 512 + m0 + m) * DD + n4) = acc[m];
}

// ---------- reduce dec partials + bias -> decT[b][n][ks] bf16 ----------
__global__ void red_dec(const float* __restrict__ pd, const float* __restrict__ decB,
                        u16* __restrict__ decT) {
  __shared__ u16 st[64][34];
  int nt = blockIdx.x, b = blockIdx.y;
  int n0 = nt * 32;
  int t = threadIdx.x;
  int nn = t & 31, kg = t >> 5;
  float db = decB[n0 + nn];
#pragma unroll
  for (int ki = 0; ki < 8; ++ki) {
    int ks = kg * 8 + ki;
    float s = db;
#pragma unroll
    for (int p = 0; p < 8; ++p)
      s += pd[((size_t)p * 512 + b * NSP + ks) * DD + n0 + nn];
    st[ks][nn] = f2bf(s);
  }
  __syncthreads();
  int nr = t >> 3, kseg = (t & 7) * 8;
  uint4 v;
  v.x = st[kseg + 0][nr] | ((u32)st[kseg + 1][nr] << 16);
  v.y = st[kseg + 2][nr] | ((u32)st[kseg + 3][nr] << 16);
  v.z = st[kseg + 4][nr] | ((u32)st[kseg + 5][nr] << 16);
  v.w = st[kseg + 6][nr] | ((u32)st[kseg + 7][nr] << 16);
  *(uint4*)(decT + ((size_t)b * DD + n0 + nr) * NSP + kseg) = v;
}

// ---------- fused gate GEMM + scatter + sigmoid*flow (progressive epilogue) ----------

#define GVM(n) asm volatile("s_waitcnt vmcnt(" #n ")" ::: "memory");

#define GSTA(sl, k0, p)                                                        \
  { int e = (p)*512 + t; int row = e >> 3; int cs = ((e & 7) ^ (row & 7)) * 8; \
    gl_lds16(tokbf + (size_t)(m0 + row) * DD + (k0) + cs, &As[sl][e * 8]); }
#define GSTB(sl, k0, p)                                                        \
  { int e = (p)*512 + t; int row = e >> 3; int cs = ((e & 7) ^ (row & 7)) * 8; \
    gl_lds16(gwt + (size_t)(n0 + row) * DD + (k0) + cs, &Bs[sl][e * 8]); }
#define SAI(sl, p)                                                             \
  { int e = (p)*512 + t; int row = e >> 3; int cs = ((e & 7) ^ (row & 7)) * 8; \
    gl_lds16(inflbf + ((size_t)bb * SS + s0m + row) * NSP + cs, &As[sl][e * 8]); }
#define SBD(sl, p)                                                             \
  { int e = (p)*512 + t; int row = e >> 3; int cs = ((e & 7) ^ (row & 7)) * 8; \
    gl_lds16(decT + ((size_t)bb * DD + n0 + row) * NSP + cs, &Bs[sl][e * 8]); }

#define GLOADB(sl)                                                             \
  _Pragma("unroll")                                                            \
  for (int nf = 0; nf < 2; ++nf) {                                             \
    int br = wc * 32 + nf * 16 + l15;                                          \
    bfv[nf][0] = *(const bf16x8*)&Bs[sl][br * 64 + c0];                        \
    bfv[nf][1] = *(const bf16x8*)&Bs[sl][br * 64 + c1];                        \
  }

#define GPH(sl, mq, VMW, STG, LDB)                                             \
  {                                                                            \
    VMW                                                                        \
    __builtin_amdgcn_s_barrier();                                              \
    LDB                                                                        \
    bf16x8 af[4][2];                                                           \
    _Pragma("unroll")                                                          \
    for (int mf = 0; mf < 4; ++mf) {                                           \
      int ar = (mq)*64 + mf * 16 + l15;                                        \
      af[mf][0] = *(const bf16x8*)&As[sl][ar * 64 + c0];                       \
      af[mf][1] = *(const bf16x8*)&As[sl][ar * 64 + c1];                       \
    }                                                                          \
    STG                                                                        \
    __builtin_amdgcn_s_setprio(1);                                             \
    _Pragma("unroll")                                                          \
    for (int mf = 0; mf < 4; ++mf)                                             \
      _Pragma("unroll")                                                        \
      for (int nf = 0; nf < 2; ++nf) {                                         \
        acc[(mq)*4 + mf][nf] = __builtin_amdgcn_mfma_f32_16x16x32_bf16(af[mf][0], bfv[nf][0], acc[(mq)*4 + mf][nf], 0, 0, 0); \
        acc[(mq)*4 + mf][nf] = __builtin_amdgcn_mfma_f32_16x16x32_bf16(af[mf][1], bfv[nf][1], acc[(mq)*4 + mf][nf], 0, 0, 0); \
      }                                                                        \
    __builtin_amdgcn_s_setprio(0);                                             \
    __builtin_amdgcn_s_barrier();                                              \
  }

#define GT_FULL(sl, osl, k1)                                                   \
  {                                                                            \
    bf16x8 bfv[2][2];                                                          \
    GPH(sl, 0, GVM(3), GSTB(osl, k1, 0) GSTB(osl, k1, 1), GLOADB(sl))          \
    GPH(sl, 1, GVM(4), GSTB(osl, k1, 2) GSTB(osl, k1, 3), )                    \
    GPH(sl, 2, GVM(5), GSTA(osl, k1, 0) GSTA(osl, k1, 1), )                    \
    GPH(sl, 3, GVM(6), GSTA(osl, k1, 2) GSTA(osl, k1, 3), )                    \
  }
#define GT_LAST2(sl)                                                           \
  {                                                                            \
    bf16x8 bfv[2][2];                                                          \
    GPH(sl, 0, GVM(3), SAI(0, 0) SAI(0, 1), GLOADB(sl))                        \
    GPH(sl, 1, GVM(4), SAI(0, 2) SAI(0, 3), )                                  \
    GPH(sl, 2, GVM(5), SBD(0, 0) SBD(0, 1), )                                  \
    GPH(sl, 3, GVM(6), SBD(0, 2) SBD(0, 3), )                                  \
  }

__global__ __launch_bounds__(512, 1) void k_gate(const u16* __restrict__ tokbf,
                                                 const u16* __restrict__ gwt,
                                                 const u16* __restrict__ inflbf,
                                                 const u16* __restrict__ decT,
                                                 const float* __restrict__ gateB,
                                                 float* __restrict__ outp) {
  __shared__ u16 As[2][256 * 64];
  __shared__ u16 Bs[2][256 * 64];
  int t = threadIdx.x;
  int l = t & 63, wc = t >> 6;
  int bid = blockIdx.x;
  int wg = (bid & 7) * 32 + (bid >> 3);
  int mt = wg & 63, nt = wg >> 6;
  int m0 = mt * 256, n0 = nt * 256;
  int l15 = l & 15, lh = l >> 4;
  int x7 = l15 & 7;
  int c0 = (lh ^ x7) * 8;
  int c1 = ((4 + lh) ^ x7) * 8;
  int bb = m0 >> 11, s0m = m0 & 2047;

  f32x4 acc[16][2];
#pragma unroll
  for (int i = 0; i < 16; ++i)
#pragma unroll
    for (int j = 0; j < 2; ++j) acc[i][j] = (f32x4){0.f, 0.f, 0.f, 0.f};

  GSTB(0, 0, 0) GSTB(0, 0, 1) GSTB(0, 0, 2) GSTB(0, 0, 3)
  GSTA(0, 0, 0) GSTA(0, 0, 1) GSTA(0, 0, 2) GSTA(0, 0, 3)

#pragma unroll 1
  for (int i = 0; i < 7; ++i) {
    GT_FULL(0, 1, (2 * i + 1) * 64)
    GT_FULL(1, 0, (2 * i + 2) * 64)
  }
  GT_FULL(0, 1, 960)
  GT_LAST2(1)

  GVM(0)
  __builtin_amdgcn_s_barrier();

  {
    float gb[2];
#pragma unroll
    for (int nf = 0; nf < 2; ++nf) gb[nf] = gateB[n0 + wc * 32 + nf * 16 + l15];
    bf16x8 bfv[2][2];
    GLOADB(0)
#pragma unroll
    for (int mq = 0; mq < 4; ++mq) {
      bf16x8 af[4][2];
#pragma unroll
      for (int mf = 0; mf < 4; ++mf) {
        int ar = mq * 64 + mf * 16 + l15;
        af[mf][0] = *(const bf16x8*)&As[0][ar * 64 + c0];
        af[mf][1] = *(const bf16x8*)&As[0][ar * 64 + c1];
      }
      f32x4 accf[4][2];
#pragma unroll
      for (int mf = 0; mf < 4; ++mf)
#pragma unroll
        for (int nf = 0; nf < 2; ++nf) accf[mf][nf] = (f32x4){0.f, 0.f, 0.f, 0.f};
      __builtin_amdgcn_s_setprio(1);
#pragma unroll
      for (int mf = 0; mf < 4; ++mf)
#pragma unroll
        for (int nf = 0; nf < 2; ++nf) {
          accf[mf][nf] = __builtin_amdgcn_mfma_f32_16x16x32_bf16(af[mf][0], bfv[nf][0], accf[mf][nf], 0, 0, 0);
          accf[mf][nf] = __builtin_amdgcn_mfma_f32_16x16x32_bf16(af[mf][1], bfv[nf][1], accf[mf][nf], 0, 0, 0);
        }
      __builtin_amdgcn_s_setprio(0);
#pragma unroll
      for (int mf = 0; mf < 4; ++mf)
#pragma unroll
        for (int nf = 0; nf < 2; ++nf)
#pragma unroll
          for (int r = 0; r < 4; ++r) {
            int mr = m0 + (mq * 4 + mf) * 16 + lh * 4 + r;
            int nc = n0 + wc * 32 + nf * 16 + l15;
            float z = acc[mq * 4 + mf][nf][r] + gb[nf];
            float gate = 1.f / (1.f + __expf(-z));
            outp[(size_t)mr * DD + nc] = accf[mf][nf][r] * gate;
          }
    }
  }
}

extern "C" void kernel_launch(void* const* d_in, const int* in_sizes, int n_in,
                              void* d_out, int out_size, void* d_ws, size_t ws_size,
                              hipStream_t stream) {
  const float* tok = (const float*)d_in[0];
  const float* infl = (const float*)d_in[1];
  const float* encW = (const float*)d_in[2];
  const float* encB = (const float*)d_in[3];
  const float* trW = (const float*)d_in[4];
  const float* trB = (const float*)d_in[5];
  const float* decW = (const float*)d_in[6];
  const float* decB = (const float*)d_in[7];
  const float* gw = (const float*)d_in[8];
  const float* gateB = (const float*)d_in[9];
  float* outp = (float*)d_out;

  char* wsp = (char*)d_ws;
  u16* tokbf = (u16*)(wsp);                    // 33,554,432 B
  u16* gwt = (u16*)(wsp + 33554432);           //  2,097,152 B
  u16* inflbf = (u16*)(wsp + 35651584);        //  2,097,152 B
  u16* decT = (u16*)(wsp + 41945088);          //  1,048,576 B
  float* pe = (float*)(wsp + 42993664);        //  8,388,608 B
  float* pt = (float*)(wsp + 42993664 + 8388608);   // 8,388,608 B
  u16* inflT = (u16*)(wsp + 76548096);         //  2,097,152 B
  float* rsum = (float*)(wsp + 78645248);      //     65,536 B
  float* scratch = (float*)(wsp + 78710784);   // 16,777,216 B: pg then pd

  k_prep<<<dim3(9472), dim3(256), 0, stream>>>(tok, infl, gw, tokbf, inflbf,
                                               inflT, rsum, gwt);
  k_gather_mfma<<<dim3(16, 8, 4), dim3(256), 0, stream>>>(inflT, tokbf, scratch);
  k_enc_part<<<dim3(8, 64), dim3(256), 0, stream>>>(scratch, rsum, encW, pe);
  k_trans_part<<<dim3(8, 64), dim3(256), 0, stream>>>(pe, encB, trW, pt);
  k_dec_part<<<dim3(8, 64), dim3(256), 0, stream>>>(pt, trB, decW, scratch);
  red_dec<<<dim3(32, 8), dim3(256), 0, stream>>>(scratch, decB, decT);
  k_gate<<<dim3(256), dim3(512), 0, stream>>>(tokbf, gwt, inflbf, decT, gateB, outp);
}

// Round 21
// 147.429 us; speedup vs baseline: 1.0751x; 1.0065x over previous
//
#include <hip/hip_runtime.h>

#define BB 8
#define SS 2048
#define DD 1024
#define BDD 512
#define NSP 64

typedef __attribute__((ext_vector_type(8))) short bf16x8;
typedef __attribute__((ext_vector_type(4))) float f32x4;
typedef unsigned short u16;
typedef unsigned int u32;

__device__ __forceinline__ u16 f2bf(float f) {
  u32 u = __builtin_bit_cast(u32, f);
  u = u + 0x7fffu + ((u >> 16) & 1u);
  return (u16)(u >> 16);
}

__device__ __forceinline__ void gl_lds16(const void* g, void* l) {
  __builtin_amdgcn_global_load_lds((const __attribute__((address_space(1))) void*)g,
                                   (__attribute__((address_space(3))) void*)l,
                                   16, 0, 0);
}

// ---------- merged prep: tok streaming cvt | infl cvt+panelT+colsum | gate_W^T ----------
// grid 9472: [0,8192) tok cvt (no LDS), [8192,8448) infl, [8448,9472) gatewt
__global__ void k_prep(const float* __restrict__ tok, const float* __restrict__ infl,
                       const float* __restrict__ gw, u16* __restrict__ tokbf,
                       u16* __restrict__ inflbf, u16* __restrict__ inflT,
                       float* __restrict__ rsum, u16* __restrict__ gwt) {
  __shared__ __align__(16) char smraw[64 * 80 * 2 + 32 * 64 * 4];
  u16(*tile)[80] = (u16(*)[80])smraw;
  float(*ps)[64] = (float(*)[64])(smraw + 64 * 80 * 2);
  float(*gt)[33] = (float(*)[33])smraw;
  int bid = blockIdx.x;
  int t = threadIdx.x;

  if (bid < 8192) {
    size_t i = ((size_t)bid * 256 + t) * 8;
    float4 a = *(const float4*)(tok + i);
    float4 bq = *(const float4*)(tok + i + 4);
    uint4 v;
    v.x = f2bf(a.x) | ((u32)f2bf(a.y) << 16);
    v.y = f2bf(a.z) | ((u32)f2bf(a.w) << 16);
    v.z = f2bf(bq.x) | ((u32)f2bf(bq.y) << 16);
    v.w = f2bf(bq.z) | ((u32)f2bf(bq.w) << 16);
    *(uint4*)(tokbf + i) = v;
  } else if (bid < 8448) {
    int R0 = (bid - 8192) * 64;
    int b = R0 >> 11, s0 = R0 & 2047;
    int st = s0 >> 6;
    int lr = t >> 3, lc = (t & 7) * 8;
    float col[8];
#pragma unroll
    for (int j = 0; j < 8; ++j) col[j] = 0.f;
#pragma unroll
    for (int i = 0; i < 2; ++i) {
      int r = lr + i * 32;
      const float* src = infl + (size_t)(R0 + r) * NSP + lc;
      float4 a = *(const float4*)src;
      float4 bq = *(const float4*)(src + 4);
      col[0] += a.x; col[1] += a.y; col[2] += a.z; col[3] += a.w;
      col[4] += bq.x; col[5] += bq.y; col[6] += bq.z; col[7] += bq.w;
      uint4 v;
      v.x = f2bf(a.x) | ((u32)f2bf(a.y) << 16);
      v.y = f2bf(a.z) | ((u32)f2bf(a.w) << 16);
      v.z = f2bf(bq.x) | ((u32)f2bf(bq.y) << 16);
      v.w = f2bf(bq.z) | ((u32)f2bf(bq.w) << 16);
      *(uint4*)(inflbf + (size_t)(R0 + r) * NSP + lc) = v;
      *(uint4*)&tile[r][lc] = v;
    }
#pragma unroll
    for (int j = 0; j < 8; ++j) ps[lr][lc + j] = col[j];
    __syncthreads();
    if (t < 64) {
      float s = 0.f;
#pragma unroll
      for (int rr = 0; rr < 32; ++rr) s += ps[rr][t];
      rsum[((size_t)b * 32 + st) * 64 + t] = s;
    }
    int sseg = (t & 7) * 8;
    size_t ibase = (size_t)b * NSP * SS + (size_t)st * (NSP * 64);
#pragma unroll
    for (int i = 0; i < 2; ++i) {
      int dcol = (t >> 3) + i * 32;
      u16 a0 = tile[sseg + 0][dcol], a1 = tile[sseg + 1][dcol];
      u16 a2 = tile[sseg + 2][dcol], a3 = tile[sseg + 3][dcol];
      u16 a4 = tile[sseg + 4][dcol], a5 = tile[sseg + 5][dcol];
      u16 a6 = tile[sseg + 6][dcol], a7 = tile[sseg + 7][dcol];
      uint4 v;
      v.x = a0 | ((u32)a1 << 16);
      v.y = a2 | ((u32)a3 << 16);
      v.z = a4 | ((u32)a5 << 16);
      v.w = a6 | ((u32)a7 << 16);
      *(uint4*)(inflT + ibase + (size_t)dcol * 64 + sseg) = v;
    }
  } else {
    int g = bid - 8448;
    int n0 = (g & 31) * 32, k0 = (g >> 5) * 32;
    int tx = t & 31, ty = t >> 5;
#pragma unroll
    for (int r = 0; r < 4; ++r) {
      int kr = ty + r * 8;
      gt[kr][tx] = gw[(k0 + kr) * DD + n0 + tx];
    }
    __syncthreads();
#pragma unroll
    for (int r = 0; r < 4; ++r) {
      int nc = ty + r * 8;
      gwt[(n0 + nc) * DD + k0 + tx] = f2bf(gt[tx][nc]);
    }
  }
}

// ---------- MFMA gather partials: pg[sq][b*64+k][d] ----------
__global__ __launch_bounds__(256) void k_gather_mfma(const u16* __restrict__ inflT,
                                                     const u16* __restrict__ tokbf,
                                                     float* __restrict__ pg) {
  __shared__ u16 As[64 * 64];
  __shared__ u16 Bs[64 * 64];
  int t = threadIdx.x;
  int l = t & 63, w = t >> 6;
  int wr = w >> 1, wc = w & 1;
  int n0 = blockIdx.x * 64;
  int b = blockIdx.y;
  int sq = blockIdx.z;
  int l15 = l & 15, lh = l >> 4;

  const u16* ap = inflT + (size_t)b * NSP * SS;
  int s = t >> 2;
  int dseg = (t & 3) * 16;

  f32x4 acc[2][2];
#pragma unroll
  for (int i = 0; i < 2; ++i)
#pragma unroll
    for (int j = 0; j < 2; ++j) acc[i][j] = (f32x4){0.f, 0.f, 0.f, 0.f};

  for (int kt = 0; kt < 8; ++kt) {
    int pc = sq * 8 + kt;
    const u16* app = ap + (size_t)pc * (NSP * 64);
#pragma unroll
    for (int i = 0; i < 2; ++i) {
      int e = i * 256 + t;
      int row = e >> 3;
      int cs = ((e & 7) ^ (row & 7)) * 8;
      gl_lds16(app + row * 64 + cs, &As[e * 8]);
    }
    {
      const u16* src = tokbf + ((size_t)(b * SS + pc * 64 + s)) * DD + n0 + dseg;
      uint4 q0 = *(const uint4*)src;
      uint4 q1 = *(const uint4*)(src + 8);
      u32 wd[8] = {q0.x, q0.y, q0.z, q0.w, q1.x, q1.y, q1.z, q1.w};
      int shi = (s >> 3), slo = (s & 7);
#pragma unroll
      for (int p = 0; p < 8; ++p) {
        int d0 = dseg + p * 2, d1 = dseg + p * 2 + 1;
        Bs[d0 * 64 + ((shi ^ ((d0 >> 3) & 7)) * 8) + slo] = (u16)wd[p];
        Bs[d1 * 64 + ((shi ^ ((d1 >> 3) & 7)) * 8) + slo] = (u16)(wd[p] >> 16);
      }
    }
    __syncthreads();
#pragma unroll
    for (int ks = 0; ks < 2; ++ks) {
      int g = ks * 4 + lh;
      bf16x8 af[2], bfv[2];
#pragma unroll
      for (int mi = 0; mi < 2; ++mi) {
        int ar = wr * 32 + mi * 16 + l15;
        af[mi] = *(const bf16x8*)&As[ar * 64 + ((g ^ (ar & 7)) * 8)];
      }
#pragma unroll
      for (int ni = 0; ni < 2; ++ni) {
        int br = wc * 32 + ni * 16 + l15;
        bfv[ni] = *(const bf16x8*)&Bs[br * 64 + ((g ^ ((br >> 3) & 7)) * 8)];
      }
#pragma unroll
      for (int mi = 0; mi < 2; ++mi)
#pragma unroll
        for (int ni = 0; ni < 2; ++ni)
          acc[mi][ni] = __builtin_amdgcn_mfma_f32_16x16x32_bf16(af[mi], bfv[ni], acc[mi][ni], 0, 0, 0);
    }
    __syncthreads();
  }

#pragma unroll
  for (int mi = 0; mi < 2; ++mi)
#pragma unroll
    for (int ni = 0; ni < 2; ++ni)
#pragma unroll
      for (int r = 0; r < 4; ++r) {
        int krow = wr * 32 + mi * 16 + lh * 4 + r;
        int dcol = n0 + wc * 32 + ni * 16 + l15;
        pg[((size_t)sq * 512 + b * NSP + krow) * DD + dcol] = acc[mi][ni][r];
      }
}

// ---------- enc partials (fused gather-reduce + inline rtot): pe[8][m][n], d-slice 128 ----------
__global__ void k_enc_part(const float* __restrict__ pg, const float* __restrict__ rsum,
                           const float* __restrict__ encW, float* __restrict__ pe) {
  __shared__ float gl[8][128];
  int dq = blockIdx.x, mt = blockIdx.y;
  int m0 = mt * 8, d0 = dq * 128;
  int t = threadIdx.x;
  {
    int r = t >> 5, c = t & 31;
    float s[4] = {0.f, 0.f, 0.f, 0.f};
#pragma unroll
    for (int q = 0; q < 4; ++q) {
      const float* qp = pg + ((size_t)q * 512 + m0 + r) * DD + d0;
      s[0] += qp[c]; s[1] += qp[c + 32]; s[2] += qp[c + 64]; s[3] += qp[c + 96];
    }
    int mrow = m0 + r;
    int bq = mrow >> 6, kq = mrow & 63;
    float tt = 0.f;
#pragma unroll
    for (int st = 0; st < 32; ++st) tt += rsum[((size_t)bq * 32 + st) * 64 + kq];
    float rt = 1.f / fmaxf(tt, 1e-8f);
    gl[r][c] = s[0] * rt;
    gl[r][c + 32] = s[1] * rt;
    gl[r][c + 64] = s[2] * rt;
    gl[r][c + 96] = s[3] * rt;
  }
  __syncthreads();
  int n4 = (t & 127) * 4, mh = (t >> 7) * 4;
  float4 acc[4];
#pragma unroll
  for (int m = 0; m < 4; ++m) acc[m] = (float4){0.f, 0.f, 0.f, 0.f};
  for (int i = 0; i < 128; ++i) {
    float4 wv = *(const float4*)(encW + (d0 + i) * BDD + n4);
#pragma unroll
    for (int m = 0; m < 4; ++m) {
      float g = gl[mh + m][i];
      acc[m].x += g * wv.x; acc[m].y += g * wv.y;
      acc[m].z += g * wv.z; acc[m].w += g * wv.w;
    }
  }
#pragma unroll
  for (int m = 0; m < 4; ++m)
    *(float4*)(pe + ((size_t)dq * 512 + m0 + mh + m) * BDD + n4) = acc[m];
}

// ---------- trans partials (fused enc-reduce + bias + relu): pt[8][b*64+ks][e], d-slice 64 ----------
__global__ void k_trans_part(const float* __restrict__ pe, const float* __restrict__ encB,
                             const float* __restrict__ trW, float* __restrict__ pt) {
  __shared__ float el[8][64];
  int dq = blockIdx.x, ks = blockIdx.y;
  int d0 = dq * 64;
  int t = threadIdx.x;
  {
    int r = t >> 5, c = t & 31;
    int m = r * NSP + ks;
    float s1 = 0.f, s2 = 0.f;
#pragma unroll
    for (int p = 0; p < 8; ++p) {
      const float* qp = pe + ((size_t)p * 512 + m) * BDD + d0;
      s1 += qp[c]; s2 += qp[c + 32];
    }
    el[r][c] = fmaxf(s1 + encB[d0 + c], 0.f);
    el[r][c + 32] = fmaxf(s2 + encB[d0 + c + 32], 0.f);
  }
  __syncthreads();
  int n4 = (t & 127) * 4, mh = (t >> 7) * 4;
  float4 acc[4];
#pragma unroll
  for (int m = 0; m < 4; ++m) acc[m] = (float4){0.f, 0.f, 0.f, 0.f};
  for (int i = 0; i < 64; ++i) {
    float4 wv = *(const float4*)(trW + ((size_t)ks * BDD + d0 + i) * BDD + n4);
#pragma unroll
    for (int m = 0; m < 4; ++m) {
      float g = el[mh + m][i];
      acc[m].x += g * wv.x; acc[m].y += g * wv.y;
      acc[m].z += g * wv.z; acc[m].w += g * wv.w;
    }
  }
#pragma unroll
  for (int m = 0; m < 4; ++m)
    *(float4*)(pt + ((size_t)dq * 512 + (mh + m) * NSP + ks) * BDD + n4) = acc[m];
}

// ---------- dec partials (fused trans-reduce + bias): pd[8][m][n] ----------
__global__ void k_dec_part(const float* __restrict__ pt, const float* __restrict__ trB,
                           const float* __restrict__ decW, float* __restrict__ pd) {
  __shared__ float tl[8][64];
  int dq = blockIdx.x, mt = blockIdx.y;
  int m0 = mt * 8, d0 = dq * 64;
  int t = threadIdx.x;
  {
    int r = t >> 5, c = t & 31;
    int m = m0 + r;
    float s1 = 0.f, s2 = 0.f;
#pragma unroll
    for (int p = 0; p < 8; ++p) {
      const float* qp = pt + ((size_t)p * 512 + m) * BDD + d0;
      s1 += qp[c]; s2 += qp[c + 32];
    }
    tl[r][c] = s1 + trB[(m & 63) * BDD + d0 + c];
    tl[r][c + 32] = s2 + trB[(m & 63) * BDD + d0 + c + 32];
  }
  __syncthreads();
  int n4 = t * 4;
  float4 acc[8];
#pragma unroll
  for (int m = 0; m < 8; ++m) acc[m] = (float4){0.f, 0.f, 0.f, 0.f};
  for (int i = 0; i < 64; ++i) {
    float4 wv = *(const float4*)(decW + (d0 + i) * DD + n4);
#pragma unroll
    for (int m = 0; m < 8; ++m) {
      float g = tl[m][i];
      acc[m].x += g * wv.x; acc[m].y += g * wv.y;
      acc[m].z += g * wv.z; acc[m].w += g * wv.w;
    }
  }
#pragma unroll
  for (int m = 0; m < 8; ++m)
    *(float4*)(pd + ((size_t)dq * 512 + m0 + m) * DD + n4) = acc[m];
}

// ---------- reduce dec partials + bias -> decT[b][n][ks] bf16 ----------
__global__ void red_dec(const float* __restrict__ pd, const float* __restrict__ decB,
                        u16* __restrict__ decT) {
  __shared__ u16 st[64][34];
  int nt = blockIdx.x, b = blockIdx.y;
  int n0 = nt * 32;
  int t = threadIdx.x;
  int nn = t & 31, kg = t >> 5;
  float db = decB[n0 + nn];
#pragma unroll
  for (int ki = 0; ki < 8; ++ki) {
    int ks = kg * 8 + ki;
    float s = db;
#pragma unroll
    for (int p = 0; p < 8; ++p)
      s += pd[((size_t)p * 512 + b * NSP + ks) * DD + n0 + nn];
    st[ks][nn] = f2bf(s);
  }
  __syncthreads();
  int nr = t >> 3, kseg = (t & 7) * 8;
  uint4 v;
  v.x = st[kseg + 0][nr] | ((u32)st[kseg + 1][nr] << 16);
  v.y = st[kseg + 2][nr] | ((u32)st[kseg + 3][nr] << 16);
  v.z = st[kseg + 4][nr] | ((u32)st[kseg + 5][nr] << 16);
  v.w = st[kseg + 6][nr] | ((u32)st[kseg + 7][nr] << 16);
  *(uint4*)(decT + ((size_t)b * DD + n0 + nr) * NSP + kseg) = v;
}

// ---------- fused gate GEMM + scatter + sigmoid*flow (progressive epilogue) ----------
// Grid map: each XCD owns 8 mt x all 4 nt -> A working set 4MB = L2-resident,
// each A row HBM-fetched once, L2-served for the other 3 n-tiles.

#define GVM(n) asm volatile("s_waitcnt vmcnt(" #n ")" ::: "memory");

#define GSTA(sl, k0, p)                                                        \
  { int e = (p)*512 + t; int row = e >> 3; int cs = ((e & 7) ^ (row & 7)) * 8; \
    gl_lds16(tokbf + (size_t)(m0 + row) * DD + (k0) + cs, &As[sl][e * 8]); }
#define GSTB(sl, k0, p)                                                        \
  { int e = (p)*512 + t; int row = e >> 3; int cs = ((e & 7) ^ (row & 7)) * 8; \
    gl_lds16(gwt + (size_t)(n0 + row) * DD + (k0) + cs, &Bs[sl][e * 8]); }
#define SAI(sl, p)                                                             \
  { int e = (p)*512 + t; int row = e >> 3; int cs = ((e & 7) ^ (row & 7)) * 8; \
    gl_lds16(inflbf + ((size_t)bb * SS + s0m + row) * NSP + cs, &As[sl][e * 8]); }
#define SBD(sl, p)                                                             \
  { int e = (p)*512 + t; int row = e >> 3; int cs = ((e & 7) ^ (row & 7)) * 8; \
    gl_lds16(decT + ((size_t)bb * DD + n0 + row) * NSP + cs, &Bs[sl][e * 8]); }

#define GLOADB(sl)                                                             \
  _Pragma("unroll")                                                            \
  for (int nf = 0; nf < 2; ++nf) {                                             \
    int br = wc * 32 + nf * 16 + l15;                                          \
    bfv[nf][0] = *(const bf16x8*)&Bs[sl][br * 64 + c0];                        \
    bfv[nf][1] = *(const bf16x8*)&Bs[sl][br * 64 + c1];                        \
  }

#define GPH(sl, mq, VMW, STG, LDB)                                             \
  {                                                                            \
    VMW                                                                        \
    __builtin_amdgcn_s_barrier();                                              \
    LDB                                                                        \
    bf16x8 af[4][2];                                                           \
    _Pragma("unroll")                                                          \
    for (int mf = 0; mf < 4; ++mf) {                                           \
      int ar = (mq)*64 + mf * 16 + l15;                                        \
      af[mf][0] = *(const bf16x8*)&As[sl][ar * 64 + c0];                       \
      af[mf][1] = *(const bf16x8*)&As[sl][ar * 64 + c1];                       \
    }                                                                          \
    STG                                                                        \
    __builtin_amdgcn_s_setprio(1);                                             \
    _Pragma("unroll")                                                          \
    for (int mf = 0; mf < 4; ++mf)                                             \
      _Pragma("unroll")                                                        \
      for (int nf = 0; nf < 2; ++nf) {                                         \
        acc[(mq)*4 + mf][nf] = __builtin_amdgcn_mfma_f32_16x16x32_bf16(af[mf][0], bfv[nf][0], acc[(mq)*4 + mf][nf], 0, 0, 0); \
        acc[(mq)*4 + mf][nf] = __builtin_amdgcn_mfma_f32_16x16x32_bf16(af[mf][1], bfv[nf][1], acc[(mq)*4 + mf][nf], 0, 0, 0); \
      }                                                                        \
    __builtin_amdgcn_s_setprio(0);                                             \
    __builtin_amdgcn_s_barrier();                                              \
  }

#define GT_FULL(sl, osl, k1)                                                   \
  {                                                                            \
    bf16x8 bfv[2][2];                                                          \
    GPH(sl, 0, GVM(3), GSTB(osl, k1, 0) GSTB(osl, k1, 1), GLOADB(sl))          \
    GPH(sl, 1, GVM(4), GSTB(osl, k1, 2) GSTB(osl, k1, 3), )                    \
    GPH(sl, 2, GVM(5), GSTA(osl, k1, 0) GSTA(osl, k1, 1), )                    \
    GPH(sl, 3, GVM(6), GSTA(osl, k1, 2) GSTA(osl, k1, 3), )                    \
  }
#define GT_LAST2(sl)                                                           \
  {                                                                            \
    bf16x8 bfv[2][2];                                                          \
    GPH(sl, 0, GVM(3), SAI(0, 0) SAI(0, 1), GLOADB(sl))                        \
    GPH(sl, 1, GVM(4), SAI(0, 2) SAI(0, 3), )                                  \
    GPH(sl, 2, GVM(5), SBD(0, 0) SBD(0, 1), )                                  \
    GPH(sl, 3, GVM(6), SBD(0, 2) SBD(0, 3), )                                  \
  }

__global__ __launch_bounds__(512, 1) void k_gate(const u16* __restrict__ tokbf,
                                                 const u16* __restrict__ gwt,
                                                 const u16* __restrict__ inflbf,
                                                 const u16* __restrict__ decT,
                                                 const float* __restrict__ gateB,
                                                 float* __restrict__ outp) {
  __shared__ u16 As[2][256 * 64];
  __shared__ u16 Bs[2][256 * 64];
  int t = threadIdx.x;
  int l = t & 63, wc = t >> 6;
  int bid = blockIdx.x;
  // L2-locality map: xcd owns 8 mt x 4 nt (A-set 4MB = L2)
  int mt = (bid & 7) * 8 + ((bid >> 3) & 7);
  int nt = bid >> 6;
  int m0 = mt * 256, n0 = nt * 256;
  int l15 = l & 15, lh = l >> 4;
  int x7 = l15 & 7;
  int c0 = (lh ^ x7) * 8;
  int c1 = ((4 + lh) ^ x7) * 8;
  int bb = m0 >> 11, s0m = m0 & 2047;

  f32x4 acc[16][2];
#pragma unroll
  for (int i = 0; i < 16; ++i)
#pragma unroll
    for (int j = 0; j < 2; ++j) acc[i][j] = (f32x4){0.f, 0.f, 0.f, 0.f};

  GSTB(0, 0, 0) GSTB(0, 0, 1) GSTB(0, 0, 2) GSTB(0, 0, 3)
  GSTA(0, 0, 0) GSTA(0, 0, 1) GSTA(0, 0, 2) GSTA(0, 0, 3)

#pragma unroll 1
  for (int i = 0; i < 7; ++i) {
    GT_FULL(0, 1, (2 * i + 1) * 64)
    GT_FULL(1, 0, (2 * i + 2) * 64)
  }
  GT_FULL(0, 1, 960)
  GT_LAST2(1)

  GVM(0)
  __builtin_amdgcn_s_barrier();

  {
    float gb[2];
#pragma unroll
    for (int nf = 0; nf < 2; ++nf) gb[nf] = gateB[n0 + wc * 32 + nf * 16 + l15];
    bf16x8 bfv[2][2];
    GLOADB(0)
#pragma unroll
    for (int mq = 0; mq < 4; ++mq) {
      bf16x8 af[4][2];
#pragma unroll
      for (int mf = 0; mf < 4; ++mf) {
        int ar = mq * 64 + mf * 16 + l15;
        af[mf][0] = *(const bf16x8*)&As[0][ar * 64 + c0];
        af[mf][1] = *(const bf16x8*)&As[0][ar * 64 + c1];
      }
      f32x4 accf[4][2];
#pragma unroll
      for (int mf = 0; mf < 4; ++mf)
#pragma unroll
        for (int nf = 0; nf < 2; ++nf) accf[mf][nf] = (f32x4){0.f, 0.f, 0.f, 0.f};
      __builtin_amdgcn_s_setprio(1);
#pragma unroll
      for (int mf = 0; mf < 4; ++mf)
#pragma unroll
        for (int nf = 0; nf < 2; ++nf) {
          accf[mf][nf] = __builtin_amdgcn_mfma_f32_16x16x32_bf16(af[mf][0], bfv[nf][0], accf[mf][nf], 0, 0, 0);
          accf[mf][nf] = __builtin_amdgcn_mfma_f32_16x16x32_bf16(af[mf][1], bfv[nf][1], accf[mf][nf], 0, 0, 0);
        }
      __builtin_amdgcn_s_setprio(0);
#pragma unroll
      for (int mf = 0; mf < 4; ++mf)
#pragma unroll
        for (int nf = 0; nf < 2; ++nf)
#pragma unroll
          for (int r = 0; r < 4; ++r) {
            int mr = m0 + (mq * 4 + mf) * 16 + lh * 4 + r;
            int nc = n0 + wc * 32 + nf * 16 + l15;
            float z = acc[mq * 4 + mf][nf][r] + gb[nf];
            float gate = 1.f / (1.f + __expf(-z));
            outp[(size_t)mr * DD + nc] = accf[mf][nf][r] * gate;
          }
    }
  }
}

extern "C" void kernel_launch(void* const* d_in, const int* in_sizes, int n_in,
                              void* d_out, int out_size, void* d_ws, size_t ws_size,
                              hipStream_t stream) {
  const float* tok = (const float*)d_in[0];
  const float* infl = (const float*)d_in[1];
  const float* encW = (const float*)d_in[2];
  const float* encB = (const float*)d_in[3];
  const float* trW = (const float*)d_in[4];
  const float* trB = (const float*)d_in[5];
  const float* decW = (const float*)d_in[6];
  const float* decB = (const float*)d_in[7];
  const float* gw = (const float*)d_in[8];
  const float* gateB = (const float*)d_in[9];
  float* outp = (float*)d_out;

  char* wsp = (char*)d_ws;
  u16* tokbf = (u16*)(wsp);                    // 33,554,432 B
  u16* gwt = (u16*)(wsp + 33554432);           //  2,097,152 B
  u16* inflbf = (u16*)(wsp + 35651584);        //  2,097,152 B
  u16* decT = (u16*)(wsp + 41945088);          //  1,048,576 B
  float* pe = (float*)(wsp + 42993664);        //  8,388,608 B
  float* pt = (float*)(wsp + 42993664 + 8388608);   // 8,388,608 B
  u16* inflT = (u16*)(wsp + 76548096);         //  2,097,152 B
  float* rsum = (float*)(wsp + 78645248);      //     65,536 B
  float* scratch = (float*)(wsp + 78710784);   // 16,777,216 B: pg then pd

  k_prep<<<dim3(9472), dim3(256), 0, stream>>>(tok, infl, gw, tokbf, inflbf,
                                               inflT, rsum, gwt);
  k_gather_mfma<<<dim3(16, 8, 4), dim3(256), 0, stream>>>(inflT, tokbf, scratch);
  k_enc_part<<<dim3(8, 64), dim3(256), 0, stream>>>(scratch, rsum, encW, pe);
  k_trans_part<<<dim3(8, 64), dim3(256), 0, stream>>>(pe, encB, trW, pt);
  k_dec_part<<<dim3(8, 64), dim3(256), 0, stream>>>(pt, trB, decW, scratch);
  red_dec<<<dim3(32, 8), dim3(256), 0, stream>>>(scratch, decB, decT);
  k_gate<<<dim3(256), dim3(512), 0, stream>>>(tokbf, gwt, inflbf, decT, gateB, outp);
}